// Round 9
// baseline (884.373 us; speedup 1.0000x reference)
//
#include <hip/hip_runtime.h>
#include <cstddef>
#include <cstdint>

#define T_U   12800   // user tokens B*S
#define T_I   1024    // item tokens B*Nc
#define CAP_U 26112   // 2*T_U + 4*128 slot capacity (128-aligned per expert)
#define CAP_I 3072    // 2*T_I + 8*128

using short8 = __attribute__((ext_vector_type(8))) short;   // 8 bf16 (4 VGPRs)
using f32x4  = __attribute__((ext_vector_type(4))) float;

__device__ __forceinline__ float gelu_f(float x) {
  return 0.5f * x * (1.0f + erff(x * 0.7071067811865476f));
}

// split fp32 -> (hi, lo) bf16 with RNE; x ~= hi + lo to ~17 mantissa bits
__device__ __forceinline__ void bf16_split(float x, unsigned short& h, unsigned short& l) {
  unsigned int u = __float_as_uint(x);
  unsigned short hs = (unsigned short)((u + 0x7FFFu + ((u >> 16) & 1u)) >> 16);
  float hf = __uint_as_float(((unsigned int)hs) << 16);
  float r = x - hf;
  unsigned int u2 = __float_as_uint(r);
  unsigned short ls = (unsigned short)((u2 + 0x7FFFu + ((u2 >> 16) & 1u)) >> 16);
  h = hs; l = ls;
}

// pack 8 fp32 -> hi/lo short8 fragments (RNE split)
__device__ __forceinline__ void split8v(float4 a, float4 b, short8& h, short8& l) {
  unsigned short hh, ll;
  bf16_split(a.x, hh, ll); h[0] = (short)hh; l[0] = (short)ll;
  bf16_split(a.y, hh, ll); h[1] = (short)hh; l[1] = (short)ll;
  bf16_split(a.z, hh, ll); h[2] = (short)hh; l[2] = (short)ll;
  bf16_split(a.w, hh, ll); h[3] = (short)hh; l[3] = (short)ll;
  bf16_split(b.x, hh, ll); h[4] = (short)hh; l[4] = (short)ll;
  bf16_split(b.y, hh, ll); h[5] = (short)hh; l[5] = (short)ll;
  bf16_split(b.z, hh, ll); h[6] = (short)hh; l[6] = (short)ll;
  bf16_split(b.w, hh, ll); h[7] = (short)hh; l[7] = (short)ll;
}

// cheap truncation split for non-negative values (softmax P): ~2^-16 rel
__device__ __forceinline__ void psplit8(float4 a, float4 b, short8& h, short8& l) {
  unsigned int u; float x;
#define PS_(VAL, i)                                     \
  u = __float_as_uint(VAL);                             \
  h[i] = (short)(u >> 16);                              \
  x = (VAL) - __uint_as_float(u & 0xFFFF0000u);         \
  l[i] = (short)(__float_as_uint(x) >> 16);
  PS_(a.x, 0) PS_(a.y, 1) PS_(a.z, 2) PS_(a.w, 3)
  PS_(b.x, 4) PS_(b.y, 5) PS_(b.z, 6) PS_(b.w, 7)
#undef PS_
}

// async global->LDS, 16B per lane. LDS dest is wave-uniform base + lane*16.
__device__ __forceinline__ void gll16(const unsigned short* g, unsigned short* l) {
  __builtin_amdgcn_global_load_lds(
      (const __attribute__((address_space(1))) unsigned int*)g,
      (__attribute__((address_space(3))) unsigned int*)l, 16, 0, 0);
}

// bare s_barrier (no vmcnt drain) with compiler memory fence
__device__ __forceinline__ void wg_barrier() {
  asm volatile("" ::: "memory");
  __builtin_amdgcn_s_barrier();
  asm volatile("" ::: "memory");
}
// counted vmcnt waits (T4): only the CURRENT buffer's gll loads are waited;
// next buffer's stay in flight across barriers. sched_barrier pins ds_reads
// behind the wait (rule #18).
#define VMWAIT(N)                                              \
  do {                                                         \
    asm volatile("s_waitcnt vmcnt(" #N ")" ::: "memory");      \
    __builtin_amdgcn_sched_barrier(0);                         \
  } while (0)

#define FMA16(a, b, acc)                                                        \
  acc[0][0] += a.x * b.x; acc[0][1] += a.x * b.y; acc[0][2] += a.x * b.z; acc[0][3] += a.x * b.w; \
  acc[1][0] += a.y * b.x; acc[1][1] += a.y * b.y; acc[1][2] += a.y * b.z; acc[1][3] += a.y * b.w; \
  acc[2][0] += a.z * b.x; acc[2][1] += a.z * b.y; acc[2][2] += a.z * b.z; acc[2][3] += a.z * b.w; \
  acc[3][0] += a.w * b.x; acc[3][1] += a.w * b.y; acc[3][2] += a.w * b.z; acc[3][3] += a.w * b.w;

// ---------------- sentinel (ws too small) ----------------
__global__ void k_sentinel(float* out) { out[0] = 1.0e9f; }

// ---------------- fused weight cvt (all 7 tensors; arena is contiguous) ----------------
// dst index == global float index; only source pointer differs per segment.
// Also zero-fills the 2KB gll pad-source region (first 512 threads).
__global__ __launch_bounds__(256) void k_cvt_all(
    const float* __restrict__ s0, const float* __restrict__ s1,
    const float* __restrict__ s2, const float* __restrict__ s3,
    const float* __restrict__ s4, const float* __restrict__ s5,
    const float* __restrict__ s6,
    unsigned short* __restrict__ hi, unsigned short* __restrict__ lo,
    float* __restrict__ zb)
{
  int i = blockIdx.x * 256 + threadIdx.x;      // float4 index, < 1228800
  if (i < 512) zb[i] = 0.f;
  const float* src; int base;
  if (i < 131072)       { if (i < 98304)  { src = s0; base = 0; }       else { src = s1; base = 98304; } }
  else if (i < 655360)  { if (i < 393216) { src = s2; base = 131072; }  else { src = s3; base = 393216; } }
  else if (i < 1179648) { if (i < 917504) { src = s4; base = 655360; }  else { src = s5; base = 917504; } }
  else                  { src = s6; base = 1179648; }
  float4 v = ((const float4*)src)[i - base];
  ushort4 h, l;
  bf16_split(v.x, h.x, l.x);
  bf16_split(v.y, h.y, l.y);
  bf16_split(v.z, h.z, l.z);
  bf16_split(v.w, h.w, l.w);
  ((ushort4*)hi)[i] = h;
  ((ushort4*)lo)[i] = l;
}

// ---------------- embedding + (faithful) RoPE + fused plane split ----------------
__global__ __launch_bounds__(256) void k_embed_rope(
    const int* __restrict__ hist, const float* __restrict__ emb, float* __restrict__ X,
    unsigned short* __restrict__ XH, unsigned short* __restrict__ XL)
{
  int t = blockIdx.x;
  int s = t % 200;
  int d = threadIdx.x;
  const float* row = emb + (size_t)hist[t] * 256;
  float x0 = row[d];
  float x1 = row[(d + 1) & 255];
  int fi = d & 127;
  float inv = expf(-9.210340371976184f * ((float)fi * (1.0f / 128.0f)));
  float ang = (float)s * inv;
  float v = x0 * cosf(ang) + x1 * sinf(ang);
  size_t idx = (size_t)t * 256 + d;
  X[idx] = v;
  unsigned short hh, ll;
  bf16_split(v, hh, ll);
  XH[idx] = hh; XL[idx] = ll;
}

// ---------------- item embedding sum + plane split + fused router<8> ----------------
__global__ __launch_bounds__(256) void k_item_embed_router(
    const int* __restrict__ cand, const int* __restrict__ catid,
    const float* __restrict__ item_emb, const float* __restrict__ cat_emb,
    float* __restrict__ IE, unsigned short* __restrict__ IH, unsigned short* __restrict__ IL,
    const float* __restrict__ gw, const float* __restrict__ gb,
    float* __restrict__ probs, int* __restrict__ ti, float* __restrict__ tw)
{
  const int E = 8;
  int t = blockIdx.x, d = threadIdx.x;
  float v = item_emb[(size_t)cand[t] * 256 + d] + cat_emb[(size_t)catid[t] * 256 + d];
  size_t idx = (size_t)t * 256 + d;
  IE[idx] = v;
  unsigned short hh, ll;
  bf16_split(v, hh, ll);
  IH[idx] = hh; IL[idx] = ll;
  // router on v
  __shared__ float redg[32];
  int lane = d & 63, wid = d >> 6;
#pragma unroll
  for (int e = 0; e < E; ++e) {
    float s = v * gw[e * 256 + d];
#pragma unroll
    for (int off = 32; off > 0; off >>= 1) s += __shfl_xor(s, off, 64);
    if (lane == 0) redg[wid * E + e] = s;
  }
  __syncthreads();
  if (d == 0) {
    float p[E];
    float m = -1e30f;
#pragma unroll
    for (int e = 0; e < E; ++e) {
      p[e] = redg[e] + redg[E + e] + redg[2 * E + e] + redg[3 * E + e] + gb[e];
      m = fmaxf(m, p[e]);
    }
    float sum = 0.f;
#pragma unroll
    for (int e = 0; e < E; ++e) { p[e] = expf(p[e] - m); sum += p[e]; }
    float inv = 1.f / sum;
#pragma unroll
    for (int e = 0; e < E; ++e) { p[e] *= inv; probs[(size_t)t * E + e] = p[e]; }
    float v1 = p[0]; int i1 = 0;
#pragma unroll
    for (int e = 1; e < E; ++e) if (p[e] > v1) { v1 = p[e]; i1 = e; }
    float v2 = -1.f; int i2 = 0;
#pragma unroll
    for (int e = 0; e < E; ++e) if (e != i1 && p[e] > v2) { v2 = p[e]; i2 = e; }
    float s2 = v1 + v2;
    ti[t * 2] = i1; ti[t * 2 + 1] = i2;
    tw[t * 2] = v1 / s2; tw[t * 2 + 1] = v2 / s2;
  }
}

// ---------------- fp32 GEMM (tiny T_I matmuls); optional dual-A (concat fusion) ----------------
// If A2 != null: logical A row = [A(256) | A2(256)], K must be 512, each ld 256.
__global__ __launch_bounds__(256) void k_gemm(
    const float* __restrict__ A, const float* __restrict__ A2,
    const float* __restrict__ Wm,
    const float* __restrict__ bias, float* __restrict__ C,
    int M, int N, int K, int act)
{
  __shared__ float As[16][68];
  __shared__ float Ws[16][68];
  int tid = threadIdx.x;
  int row0 = blockIdx.y << 6;
  int col0 = blockIdx.x << 6;
  int lr = tid >> 2, lk = (tid & 3) << 2;
  int tx = tid & 15, ty = tid >> 4;
  const float* Wload = Wm + (size_t)(col0 + lr) * K + lk;
  float acc[4][4] = {};
  for (int k0 = 0; k0 < K; k0 += 16) {
    int kk = k0 + lk;
    const float* ap;
    if (A2) ap = (kk < 256) ? A + (size_t)(row0 + lr) * 256 + kk
                            : A2 + (size_t)(row0 + lr) * 256 + (kk - 256);
    else    ap = A + (size_t)(row0 + lr) * K + kk;
    float4 av = *(const float4*)ap;
    float4 wv = *(const float4*)(Wload + k0);
    As[lk][lr] = av.x; As[lk + 1][lr] = av.y; As[lk + 2][lr] = av.z; As[lk + 3][lr] = av.w;
    Ws[lk][lr] = wv.x; Ws[lk + 1][lr] = wv.y; Ws[lk + 2][lr] = wv.z; Ws[lk + 3][lr] = wv.w;
    __syncthreads();
#pragma unroll
    for (int k = 0; k < 16; ++k) {
      float4 a = *(const float4*)&As[k][ty << 2];
      float4 b = *(const float4*)&Ws[k][tx << 2];
      FMA16(a, b, acc);
    }
    __syncthreads();
  }
#pragma unroll
  for (int i = 0; i < 4; ++i) {
    int r = row0 + (ty << 2) + i;
    int c0 = col0 + (tx << 2);
    float4 v;
    v.x = acc[i][0]; v.y = acc[i][1]; v.z = acc[i][2]; v.w = acc[i][3];
    if (bias) { v.x += bias[c0]; v.y += bias[c0 + 1]; v.z += bias[c0 + 2]; v.w += bias[c0 + 3]; }
    if (act) { v.x = gelu_f(v.x); v.y = gelu_f(v.y); v.z = gelu_f(v.z); v.w = gelu_f(v.w); }
    *(float4*)(C + (size_t)r * N + c0) = v;
  }
}

// ---------------- MFMA GEMM, split-bf16 (3-product), 128x128 tile ----------------
// gll staging, double-buffered LDS, T4 counted-vmcnt pipeline: per step
// {STAGE(next); vmcnt(8) [waits CURRENT buf only]; s_barrier; COMPUTE;
// s_barrier} — next buf's 8 gll stay in flight across both barriers.
// LDS row: [row][8x16B chunks]=hi|lo, phys chunk = logical ^ (row&7).
// Epilogue bounces through dead staging LDS for full-line stores.
// Pad rows (tok<0) source a zeroed global buffer. K mult of 32, K<=512.
__global__ __launch_bounds__(256, 2) void k_mfmm(
    const unsigned short* __restrict__ Ahi, const unsigned short* __restrict__ Alo,
    const int* __restrict__ tok, const int* __restrict__ offs, int E,
    const unsigned short* __restrict__ Whi, const unsigned short* __restrict__ Wlo,
    const float* __restrict__ bias, const unsigned short* __restrict__ zbuf,
    float* __restrict__ OutF, unsigned short* __restrict__ OutHi,
    unsigned short* __restrict__ OutLo,
    int N, int K, int ldOut, int act)
{
  int row0 = blockIdx.y << 7;
  const float* bp = bias;
  const unsigned short* Wh = Whi;
  const unsigned short* Wl = Wlo;
  if (offs) {
    if (row0 >= offs[E]) return;
    int e = E - 1;
    while (e > 0 && offs[e] > row0) --e;
    Wh += (size_t)e * N * K;
    Wl += (size_t)e * N * K;
    bp += (size_t)e * N;
  }
  int col0 = blockIdx.x << 7;
  __shared__ __align__(16) unsigned short smem[32768];   // 64 KB
  unsigned short* sA = smem;            // 2 bufs x 8192 shorts
  unsigned short* sW = smem + 16384;    // 2 bufs x 8192 shorts
  int tid = threadIdx.x, lane = tid & 63, w = tid >> 6;

  const unsigned short* srcA[4];
  const unsigned short* srcW[4];
  int ldsOff[4];
  {
    int rsub = lane >> 3, c = lane & 7;
#pragma unroll
    for (int j = 0; j < 4; ++j) {
      int q = w * 4 + j;
      int r = q * 8 + rsub;                 // 0..127
      int lc = c ^ (r & 7);                 // logical chunk stored here
      const unsigned short *ph, *pl;
      if (tok) {
        int t = tok[row0 + r];
        if (t < 0) { ph = zbuf; pl = zbuf; }
        else { ph = Ahi + (size_t)t * K; pl = Alo + (size_t)t * K; }
      } else {
        ph = Ahi + (size_t)(row0 + r) * K;
        pl = Alo + (size_t)(row0 + r) * K;
      }
      srcA[j] = (lc < 4) ? (ph + lc * 8) : (pl + (lc - 4) * 8);
      const unsigned short* wh = Wh + (size_t)(col0 + r) * K;
      const unsigned short* wl = Wl + (size_t)(col0 + r) * K;
      srcW[j] = (lc < 4) ? (wh + lc * 8) : (wl + (lc - 4) * 8);
      ldsOff[j] = q * 512;                  // shorts; wave-uniform
    }
  }

  int wv = w, fr = lane & 15, g = lane >> 4;
  int wr = (wv & 1) << 6, wc = (wv >> 1) << 6;
  int swh = (g ^ (fr & 7)) * 8;             // phys offset of hi chunk g (shorts)
  int swl = ((g | 4) ^ (fr & 7)) * 8;       // phys offset of lo chunk g

  f32x4 acc[4][4] = {};

  auto STAGE = [&](int buf, int k0) {
    unsigned short* a = sA + buf * 8192;
    unsigned short* b = sW + buf * 8192;
#pragma unroll
    for (int j = 0; j < 4; ++j) {
      gll16(srcA[j] + k0, a + ldsOff[j]);
      gll16(srcW[j] + k0, b + ldsOff[j]);
    }
  };
  auto COMPUTE = [&](int buf) {
    const unsigned short* a = sA + buf * 8192;
    const unsigned short* b = sW + buf * 8192;
    short8 ah[4], al[4], bh[4], bl[4];
#pragma unroll
    for (int mi = 0; mi < 4; ++mi) {
      int ro = (wr + mi * 16 + fr) * 64;
      ah[mi] = *(const short8*)(a + ro + swh);
      al[mi] = *(const short8*)(a + ro + swl);
    }
#pragma unroll
    for (int ni = 0; ni < 4; ++ni) {
      int ro = (wc + ni * 16 + fr) * 64;
      bh[ni] = *(const short8*)(b + ro + swh);
      bl[ni] = *(const short8*)(b + ro + swl);
    }
#pragma unroll
    for (int mi = 0; mi < 4; ++mi) {
#pragma unroll
      for (int ni = 0; ni < 4; ++ni) {
        acc[mi][ni] = __builtin_amdgcn_mfma_f32_16x16x32_bf16(ah[mi], bh[ni], acc[mi][ni], 0, 0, 0);
        acc[mi][ni] = __builtin_amdgcn_mfma_f32_16x16x32_bf16(ah[mi], bl[ni], acc[mi][ni], 0, 0, 0);
        acc[mi][ni] = __builtin_amdgcn_mfma_f32_16x16x32_bf16(al[mi], bh[ni], acc[mi][ni], 0, 0, 0);
      }
    }
  };

  int steps = K >> 5;
  STAGE(0, 0);
  for (int s = 0; s < steps; ++s) {
    bool more = (s + 1 < steps);
    if (more) STAGE((s + 1) & 1, (s + 1) << 5);   // +8 in flight
    if (more) VMWAIT(8); else VMWAIT(0);          // wait buf-s only
    wg_barrier();                                 // buf-s visible to all
    COMPUTE(s & 1);
    wg_barrier();                                 // read-join before overwrite
  }

  // ---- epilogue via LDS bounce (coalesced full-line stores) ----
  int fr4 = g << 2;
  if (OutF) {
    float* eo = (float*)smem;                 // [128][128] fp32 (64 KB)
#pragma unroll
    for (int ni = 0; ni < 4; ++ni) {
      int c = wc + ni * 16 + fr;
      float bv = bp[col0 + c];
#pragma unroll
      for (int mi = 0; mi < 4; ++mi) {
#pragma unroll
        for (int r = 0; r < 4; ++r) {
          float v = acc[mi][ni][r] + bv;
          if (act) v = gelu_f(v);
          eo[(wr + mi * 16 + fr4 + r) * 128 + c] = v;
        }
      }
    }
    __syncthreads();
#pragma unroll
    for (int i = 0; i < 16; ++i) {
      int ci = i * 256 + tid;                 // 4096 chunks of 16B
      int rr = ci >> 5, cc = ci & 31;
      float4 v = *(const float4*)(eo + rr * 128 + cc * 4);
      *(float4*)(OutF + (size_t)(row0 + rr) * ldOut + col0 + cc * 4) = v;
    }
  } else {
    unsigned short* eh = smem;                // [128][128] hi plane
    unsigned short* el = smem + 16384;        // [128][128] lo plane
#pragma unroll
    for (int ni = 0; ni < 4; ++ni) {
      int c = wc + ni * 16 + fr;
      float bv = bp[col0 + c];
#pragma unroll
      for (int mi = 0; mi < 4; ++mi) {
#pragma unroll
        for (int r = 0; r < 4; ++r) {
          float v = acc[mi][ni][r] + bv;
          if (act) v = gelu_f(v);
          unsigned short h, l;
          bf16_split(v, h, l);
          int o2 = (wr + mi * 16 + fr4 + r) * 128 + c;
          eh[o2] = h; el[o2] = l;
        }
      }
    }
    __syncthreads();
#pragma unroll
    for (int i = 0; i < 8; ++i) {
      int ci = i * 256 + tid;                 // 2048 chunks of 16B per plane
      int rr = ci >> 4, cc = ci & 15;
      uint4 vh = *(const uint4*)(eh + rr * 128 + cc * 8);
      uint4 vl = *(const uint4*)(el + rr * 128 + cc * 8);
      *(uint4*)(OutHi + (size_t)(row0 + rr) * ldOut + col0 + cc * 8) = vh;
      *(uint4*)(OutLo + (size_t)(row0 + rr) * ldOut + col0 + cc * 8) = vl;
    }
  }
}

// ---------------- MFMA GEMM variant: 64 rows x 256 cols per block ----------------
// Sole reader+writer of its rows (safe for in-place H->Y). Same gll staging +
// T4 counted vmcnt (10 gll/stage); epilogue bounces through dead W LDS.
__global__ __launch_bounds__(256, 2) void k_mfmm_y(
    const unsigned short* __restrict__ Ahi, const unsigned short* __restrict__ Alo,
    const int* __restrict__ offs, int E,
    const unsigned short* __restrict__ Whi, const unsigned short* __restrict__ Wlo,
    const float* __restrict__ bias, float* __restrict__ OutF, int K)
{
  const int N = 256;
  int row0 = blockIdx.y << 6;
  if (row0 >= offs[E]) return;
  int e = E - 1;
  while (e > 0 && offs[e] > row0) --e;
  const unsigned short* Wh = Whi + (size_t)e * N * K;
  const unsigned short* Wl = Wlo + (size_t)e * N * K;
  const float* bp = bias + (size_t)e * N;
  __shared__ __align__(16) unsigned short smem[40960];   // 80 KB
  unsigned short* sA = smem;            // 2 bufs x 4096 shorts (16 KB)
  unsigned short* sW = smem + 8192;     // 2 bufs x 16384 shorts (64 KB)
  int tid = threadIdx.x, lane = tid & 63, w = tid >> 6;

  const unsigned short* srcA[2];
  const unsigned short* srcW[8];
  int ldsAOff[2], ldsWOff[8];
  {
    int rsub = lane >> 3, c = lane & 7;
#pragma unroll
    for (int j = 0; j < 2; ++j) {
      int q = w * 2 + j;
      int r = q * 8 + rsub;                 // 0..63
      int lc = c ^ (r & 7);
      const unsigned short* ph = Ahi + (size_t)(row0 + r) * K;
      const unsigned short* pl = Alo + (size_t)(row0 + r) * K;
      srcA[j] = (lc < 4) ? (ph + lc * 8) : (pl + (lc - 4) * 8);
      ldsAOff[j] = q * 512;
    }
#pragma unroll
    for (int j = 0; j < 8; ++j) {
      int q = w * 8 + j;
      int r = q * 8 + rsub;                 // 0..255
      int lc = c ^ (r & 7);
      const unsigned short* wh = Wh + (size_t)r * K;
      const unsigned short* wl = Wl + (size_t)r * K;
      srcW[j] = (lc < 4) ? (wh + lc * 8) : (wl + (lc - 4) * 8);
      ldsWOff[j] = q * 512;
    }
  }

  int fr = lane & 15, g = lane >> 4;
  int wc = w << 6;                          // wave covers cols [wc, wc+64)
  int swh = (g ^ (fr & 7)) * 8;
  int swl = ((g | 4) ^ (fr & 7)) * 8;

  f32x4 acc[4][4] = {};

  auto STAGE = [&](int buf, int k0) {
    unsigned short* a = sA + buf * 4096;
    unsigned short* b = sW + buf * 16384;
#pragma unroll
    for (int j = 0; j < 2; ++j) gll16(srcA[j] + k0, a + ldsAOff[j]);
#pragma unroll
    for (int j = 0; j < 8; ++j) gll16(srcW[j] + k0, b + ldsWOff[j]);
  };
  auto COMPUTE = [&](int buf) {
    const unsigned short* a = sA + buf * 4096;
    const unsigned short* b = sW + buf * 16384;
    short8 ah[4], al[4], bh[4], bl[4];
#pragma unroll
    for (int mi = 0; mi < 4; ++mi) {
      int ro = (mi * 16 + fr) * 64;
      ah[mi] = *(const short8*)(a + ro + swh);
      al[mi] = *(const short8*)(a + ro + swl);
    }
#pragma unroll
    for (int ni = 0; ni < 4; ++ni) {
      int ro = (wc + ni * 16 + fr) * 64;
      bh[ni] = *(const short8*)(b + ro + swh);
      bl[ni] = *(const short8*)(b + ro + swl);
    }
#pragma unroll
    for (int mi = 0; mi < 4; ++mi) {
#pragma unroll
      for (int ni = 0; ni < 4; ++ni) {
        acc[mi][ni] = __builtin_amdgcn_mfma_f32_16x16x32_bf16(ah[mi], bh[ni], acc[mi][ni], 0, 0, 0);
        acc[mi][ni] = __builtin_amdgcn_mfma_f32_16x16x32_bf16(ah[mi], bl[ni], acc[mi][ni], 0, 0, 0);
        acc[mi][ni] = __builtin_amdgcn_mfma_f32_16x16x32_bf16(al[mi], bh[ni], acc[mi][ni], 0, 0, 0);
      }
    }
  };

  int steps = K >> 5;
  STAGE(0, 0);
  for (int s = 0; s < steps; ++s) {
    bool more = (s + 1 < steps);
    if (more) STAGE((s + 1) & 1, (s + 1) << 5);   // +10 in flight
    if (more) VMWAIT(10); else VMWAIT(0);         // wait buf-s only
    wg_barrier();
    COMPUTE(s & 1);
    wg_barrier();
  }

  // ---- epilogue via LDS bounce ----
  int fr4 = g << 2;
  float* eo = (float*)(smem + 8192);        // [64][256] fp32 (64 KB, over sW)
#pragma unroll
  for (int ni = 0; ni < 4; ++ni) {
    int c = wc + ni * 16 + fr;
    float bv = bp[c];
#pragma unroll
    for (int mi = 0; mi < 4; ++mi) {
#pragma unroll
      for (int r = 0; r < 4; ++r) {
        eo[(mi * 16 + fr4 + r) * 256 + c] = acc[mi][ni][r] + bv;
      }
    }
  }
  __syncthreads();
#pragma unroll
  for (int i = 0; i < 16; ++i) {
    int ci = i * 256 + tid;                 // 4096 chunks of 16B
    int rr = ci >> 6, cc = ci & 63;
    float4 v = *(const float4*)(eo + rr * 256 + cc * 4);
    *(float4*)(OutF + (size_t)(row0 + rr) * 256 + cc * 4) = v;
  }
}

// ---------------- self-attention via MFMA (split-bf16, per-wave q-tiles) ----------------
#define ATT_LDK 40    // shorts: 80B rows, 16B-aligned, <=2-way bank alias
#define ATT_LDV 216   // shorts: 432B rows, 16B-aligned, <=2-way
#define ATT_LDP 212   // floats: 848B rows, 16B-aligned, <=2-way
__global__ __launch_bounds__(256) void k_attn_mfma(
    const float* __restrict__ qkv,
    unsigned short* __restrict__ aoh, unsigned short* __restrict__ aol)
{
  __shared__ unsigned short sKh[208 * ATT_LDK];
  __shared__ unsigned short sKl[208 * ATT_LDK];
  __shared__ unsigned short sVh[32 * ATT_LDV];
  __shared__ unsigned short sVl[32 * ATT_LDV];
  __shared__ float sP[4 * 16 * ATT_LDP];
  int bh = blockIdx.x;
  int b = bh >> 3, h = bh & 7;
  const float* base = qkv + (size_t)b * 200 * 768 + h * 32;
  int tid = threadIdx.x;
  for (int i = tid; i < 1600; i += 256) {
    int s = i >> 3, d4 = (i & 7) << 2;
    float4 kv = *(const float4*)(base + (size_t)s * 768 + 256 + d4);
    float4 vv = *(const float4*)(base + (size_t)s * 768 + 512 + d4);
    ushort4 kh, kl;
    bf16_split(kv.x, kh.x, kl.x);
    bf16_split(kv.y, kh.y, kl.y);
    bf16_split(kv.z, kh.z, kl.z);
    bf16_split(kv.w, kh.w, kl.w);
    *(ushort4*)(sKh + s * ATT_LDK + d4) = kh;
    *(ushort4*)(sKl + s * ATT_LDK + d4) = kl;
    unsigned short vh, vl;
    bf16_split(vv.x, vh, vl); sVh[(d4 + 0) * ATT_LDV + s] = vh; sVl[(d4 + 0) * ATT_LDV + s] = vl;
    bf16_split(vv.y, vh, vl); sVh[(d4 + 1) * ATT_LDV + s] = vh; sVl[(d4 + 1) * ATT_LDV + s] = vl;
    bf16_split(vv.z, vh, vl); sVh[(d4 + 2) * ATT_LDV + s] = vh; sVl[(d4 + 2) * ATT_LDV + s] = vl;
    bf16_split(vv.w, vh, vl); sVh[(d4 + 3) * ATT_LDV + s] = vh; sVl[(d4 + 3) * ATT_LDV + s] = vl;
  }
  for (int i = tid; i < 8 * ATT_LDK; i += 256) {
    sKh[200 * ATT_LDK + i] = 0; sKl[200 * ATT_LDK + i] = 0;
  }
  for (int i = tid; i < 32 * 16; i += 256) {
    int d = i >> 4, c = 200 + (i & 15);
    sVh[d * ATT_LDV + c] = 0; sVl[d * ATT_LDV + c] = 0;
  }
  __syncthreads();

  int wv = tid >> 6, lane = tid & 63;
  int g = lane >> 4, fr = lane & 15;
  float* Pf = sP + wv * (16 * ATT_LDP);
  const float scale = 0.17677669529663687f;

  for (int t = wv; t < 13; t += 4) {
    int qbase = t << 4;
    int qrow = qbase + fr; if (qrow > 199) qrow = 199;
    const float* qp = base + (size_t)qrow * 768 + g * 8;
    float4 q0 = *(const float4*)qp;
    float4 q1 = *(const float4*)(qp + 4);
    short8 qah, qal;
    split8v(q0, q1, qah, qal);
    f32x4 acc[13] = {};
#pragma unroll
    for (int st = 0; st < 13; ++st) {
      int a = (st * 16 + fr) * ATT_LDK + g * 8;
      short8 bh = *(const short8*)(sKh + a);
      short8 bl = *(const short8*)(sKl + a);
      acc[st] = __builtin_amdgcn_mfma_f32_16x16x32_bf16(qah, bh, acc[st], 0, 0, 0);
      acc[st] = __builtin_amdgcn_mfma_f32_16x16x32_bf16(qah, bl, acc[st], 0, 0, 0);
      acc[st] = __builtin_amdgcn_mfma_f32_16x16x32_bf16(qal, bh, acc[st], 0, 0, 0);
    }
    float m[4] = {-1e30f, -1e30f, -1e30f, -1e30f};
#pragma unroll
    for (int st = 0; st < 13; ++st) {
      bool ok = (st * 16 + fr) < 200;
#pragma unroll
      for (int r = 0; r < 4; ++r) {
        float v = ok ? acc[st][r] * scale : -1e30f;
        acc[st][r] = v;
        m[r] = fmaxf(m[r], v);
      }
    }
#pragma unroll
    for (int r = 0; r < 4; ++r) {
      m[r] = fmaxf(m[r], __shfl_xor(m[r], 1, 64));
      m[r] = fmaxf(m[r], __shfl_xor(m[r], 2, 64));
      m[r] = fmaxf(m[r], __shfl_xor(m[r], 4, 64));
      m[r] = fmaxf(m[r], __shfl_xor(m[r], 8, 64));
    }
    float sum[4] = {0.f, 0.f, 0.f, 0.f};
#pragma unroll
    for (int st = 0; st < 13; ++st) {
      int scol = st * 16 + fr;
      bool ok = scol < 200;
#pragma unroll
      for (int r = 0; r < 4; ++r) {
        float e = ok ? __expf(acc[st][r] - m[r]) : 0.f;
        sum[r] += e;
        Pf[(g * 4 + r) * ATT_LDP + scol] = e;
      }
    }
#pragma unroll
    for (int r = 0; r < 4; ++r) {
      sum[r] += __shfl_xor(sum[r], 1, 64);
      sum[r] += __shfl_xor(sum[r], 2, 64);
      sum[r] += __shfl_xor(sum[r], 4, 64);
      sum[r] += __shfl_xor(sum[r], 8, 64);
      sum[r] = 1.f / sum[r];
    }
    f32x4 o00 = {}, o01 = {}, o10 = {}, o11 = {};
#pragma unroll
    for (int ks = 0; ks < 7; ++ks) {
      short8 pah = {}, pal = {}, v0h = {}, v0l = {}, v1h = {}, v1l = {};
      if (ks < 6 || g < 2) {
        const float* pr = Pf + fr * ATT_LDP + ks * 32 + g * 8;
        float4 p0 = *(const float4*)pr;
        float4 p1 = *(const float4*)(pr + 4);
        psplit8(p0, p1, pah, pal);
        int ko = ks * 32 + g * 8;
        v0h = *(const short8*)(sVh + fr * ATT_LDV + ko);
        v0l = *(const short8*)(sVl + fr * ATT_LDV + ko);
        v1h = *(const short8*)(sVh + (16 + fr) * ATT_LDV + ko);
        v1l = *(const short8*)(sVl + (16 + fr) * ATT_LDV + ko);
      }
      if (ks & 1) {
        o01 = __builtin_amdgcn_mfma_f32_16x16x32_bf16(pah, v0h, o01, 0, 0, 0);
        o01 = __builtin_amdgcn_mfma_f32_16x16x32_bf16(pah, v0l, o01, 0, 0, 0);
        o01 = __builtin_amdgcn_mfma_f32_16x16x32_bf16(pal, v0h, o01, 0, 0, 0);
        o11 = __builtin_amdgcn_mfma_f32_16x16x32_bf16(pah, v1h, o11, 0, 0, 0);
        o11 = __builtin_amdgcn_mfma_f32_16x16x32_bf16(pah, v1l, o11, 0, 0, 0);
        o11 = __builtin_amdgcn_mfma_f32_16x16x32_bf16(pal, v1h, o11, 0, 0, 0);
      } else {
        o00 = __builtin_amdgcn_mfma_f32_16x16x32_bf16(pah, v0h, o00, 0, 0, 0);
        o00 = __builtin_amdgcn_mfma_f32_16x16x32_bf16(pah, v0l, o00, 0, 0, 0);
        o00 = __builtin_amdgcn_mfma_f32_16x16x32_bf16(pal, v0h, o00, 0, 0, 0);
        o10 = __builtin_amdgcn_mfma_f32_16x16x32_bf16(pah, v1h, o10, 0, 0, 0);
        o10 = __builtin_amdgcn_mfma_f32_16x16x32_bf16(pah, v1l, o10, 0, 0, 0);
        o10 = __builtin_amdgcn_mfma_f32_16x16x32_bf16(pal, v1h, o10, 0, 0, 0);
      }
    }
#pragma unroll
    for (int r = 0; r < 4; ++r) {
      int qr = qbase + g * 4 + r;
      if (qr < 200) {
        size_t ob = (size_t)(b * 200 + qr) * 256 + h * 32;
        unsigned short hh, ll;
        bf16_split((o00[r] + o01[r]) * sum[r], hh, ll);
        aoh[ob + fr] = hh;      aol[ob + fr] = ll;
        bf16_split((o10[r] + o11[r]) * sum[r], hh, ll);
        aoh[ob + 16 + fr] = hh; aol[ob + 16 + fr] = ll;
      }
    }
  }
}

// ---------------- cross-attention ----------------
__global__ __launch_bounds__(256) void k_xattn(
    const float* __restrict__ Q, const float* __restrict__ Kb,
    const float* __restrict__ Vb, float* __restrict__ O)
{
  __shared__ float4 Ks[200 * 9];
  __shared__ float4 Vs[200 * 9];
  __shared__ float4 Qs[16 * 9];
  __shared__ float  Sc[16 * 209];
  __shared__ float  red[16 * 16];
  __shared__ float  mq_s[16], linv_s[16];
  int bh = blockIdx.x;
  int b = bh >> 3, h = bh & 7;
  int tid = threadIdx.x;
  for (int i = tid; i < 1600; i += 256) {
    int s = i >> 3, d = i & 7;
    Ks[s * 9 + d] = *(const float4*)(Kb + (size_t)(b * 200 + s) * 256 + h * 32 + d * 4);
    Vs[s * 9 + d] = *(const float4*)(Vb + (size_t)(b * 200 + s) * 256 + h * 32 + d * 4);
  }
  if (tid < 128) {
    int q = tid >> 3, d = tid & 7;
    Qs[q * 9 + d] = *(const float4*)(Q + (size_t)(b * 16 + q) * 256 + h * 32 + d * 4);
  }
  __syncthreads();
  const float scale = 0.17677669529663687f;
  int q = tid >> 4, si = tid & 15;
  float4 qr[8];
#pragma unroll
  for (int d = 0; d < 8; ++d) qr[d] = Qs[q * 9 + d];
  float sc[13];
  float lm = -1e30f;
#pragma unroll
  for (int j = 0; j < 13; ++j) {
    int s = si + 16 * j;
    if (s < 200) {
      float acc = 0.f;
#pragma unroll
      for (int d = 0; d < 8; ++d) {
        float4 kk = Ks[s * 9 + d];
        acc += qr[d].x * kk.x + qr[d].y * kk.y + qr[d].z * kk.z + qr[d].w * kk.w;
      }
      float v = acc * scale;
      sc[j] = v;
      lm = fmaxf(lm, v);
    }
  }
  red[q * 16 + si] = lm;
  __syncthreads();
  if (tid < 16) {
    float m = red[tid * 16];
#pragma unroll
    for (int k = 1; k < 16; ++k) m = fmaxf(m, red[tid * 16 + k]);
    mq_s[tid] = m;
  }
  __syncthreads();
  float mq = mq_s[q];
  float ls = 0.f;
#pragma unroll
  for (int j = 0; j < 13; ++j) {
    int s = si + 16 * j;
    if (s < 200) {
      float e = expf(sc[j] - mq);
      Sc[q * 209 + s] = e;
      ls += e;
    }
  }
  red[q * 16 + si] = ls;
  __syncthreads();
  if (tid < 16) {
    float s = 0.f;
#pragma unroll
    for (int k = 0; k < 16; ++k) s += red[tid * 16 + k];
    linv_s[tid] = 1.f / s;
  }
  __syncthreads();
  if (tid < 128) {
    int qq = tid >> 3, dd = tid & 7;
    float4 o = make_float4(0.f, 0.f, 0.f, 0.f);
    const float* prow = &Sc[qq * 209];
    for (int s = 0; s < 200; ++s) {
      float p = prow[s];
      float4 vv = Vs[s * 9 + dd];
      o.x += p * vv.x; o.y += p * vv.y; o.z += p * vv.z; o.w += p * vv.w;
    }
    float inv = linv_s[qq];
    o.x *= inv; o.y *= inv; o.z *= inv; o.w *= inv;
    *(float4*)(O + (size_t)(b * 16 + qq) * 256 + h * 32 + dd * 4) = o;
  }
}

// ---------------- LayerNorm (optional residual, optional fused plane split) ----------------
__global__ __launch_bounds__(256) void k_ln(
    const float* __restrict__ Xin, const float* __restrict__ R,
    const float* __restrict__ sc, const float* __restrict__ bi, float* __restrict__ Y,
    unsigned short* __restrict__ oh, unsigned short* __restrict__ ol)
{
  int t = blockIdx.x, d = threadIdx.x;
  size_t idx = (size_t)t * 256 + d;
  float v = Xin[idx];
  if (R) v += R[idx];
  __shared__ float red[8];
  int lane = d & 63, wid = d >> 6;
  float s = v;
#pragma unroll
  for (int off = 32; off > 0; off >>= 1) s += __shfl_xor(s, off, 64);
  if (lane == 0) red[wid] = s;
  __syncthreads();
  float mean = (red[0] + red[1] + red[2] + red[3]) * 0.00390625f;
  float dv = v - mean;
  float s2 = dv * dv;
#pragma unroll
  for (int off = 32; off > 0; off >>= 1) s2 += __shfl_xor(s2, off, 64);
  if (lane == 0) red[4 + wid] = s2;
  __syncthreads();
  float var = (red[4] + red[5] + red[6] + red[7]) * 0.00390625f;
  float y = dv * (1.0f / sqrtf(var + 1e-5f)) * sc[d] + bi[d];
  Y[idx] = y;
  if (oh) {
    unsigned short hh, ll;
    bf16_split(y, hh, ll);
    oh[idx] = hh; ol[idx] = ll;
  }
}

// ---------------- LayerNorm + plane split + fused router<E> ----------------
template <int E>
__global__ __launch_bounds__(256) void k_ln_router(
    const float* __restrict__ Xin, const float* __restrict__ R,
    const float* __restrict__ sc, const float* __restrict__ bi, float* __restrict__ Y,
    unsigned short* __restrict__ oh, unsigned short* __restrict__ ol,
    const float* __restrict__ gw, const float* __restrict__ gb,
    float* __restrict__ probs, int* __restrict__ ti, float* __restrict__ tw)
{
  int t = blockIdx.x, d = threadIdx.x;
  size_t idx = (size_t)t * 256 + d;
  float v = Xin[idx] + R[idx];
  __shared__ float red[8];
  __shared__ float redg[4 * E];
  int lane = d & 63, wid = d >> 6;
  float s = v;
#pragma unroll
  for (int off = 32; off > 0; off >>= 1) s += __shfl_xor(s, off, 64);
  if (lane == 0) red[wid] = s;
  __syncthreads();
  float mean = (red[0] + red[1] + red[2] + red[3]) * 0.00390625f;
  float dv = v - mean;
  float s2 = dv * dv;
#pragma unroll
  for (int off = 32; off > 0; off >>= 1) s2 += __shfl_xor(s2, off, 64);
  if (lane == 0) red[4 + wid] = s2;
  __syncthreads();
  float var = (red[4] + red[5] + red[6] + red[7]) * 0.00390625f;
  float y = dv * (1.0f / sqrtf(var + 1e-5f)) * sc[d] + bi[d];
  Y[idx] = y;
  unsigned short hh, ll;
  bf16_split(y, hh, ll);
  oh[idx] = hh; ol[idx] = ll;
  // router on y
#pragma unroll
  for (int e = 0; e < E; ++e) {
    float g = y * gw[e * 256 + d];
#pragma unroll
    for (int off = 32; off > 0; off >>= 1) g += __shfl_xor(g, off, 64);
    if (lane == 0) redg[wid * E + e] = g;
  }
  __syncthreads();
  if (d == 0) {
    float p[E];
    float m = -1e30f;
#pragma unroll
    for (int e = 0; e < E; ++e) {
      p[e] = redg[e] + redg[E + e] + redg[2 * E + e] + redg[3 * E + e] + gb[e];
      m = fmaxf(m, p[e]);
    }
    float sum = 0.f;
#pragma unroll
    for (int e = 0; e < E; ++e) { p[e] = expf(p[e] - m); sum += p[e]; }
    float inv = 1.f / sum;
#pragma unroll
    for (int e = 0; e < E; ++e) { p[e] *= inv; probs[(size_t)t * E + e] = p[e]; }
    float v1 = p[0]; int i1 = 0;
#pragma unroll
    for (int e = 1; e < E; ++e) if (p[e] > v1) { v1 = p[e]; i1 = e; }
    float v2 = -1.f; int i2 = 0;
#pragma unroll
    for (int e = 0; e < E; ++e) if (e != i1 && p[e] > v2) { v2 = p[e]; i2 = e; }
    float sx = v1 + v2;
    ti[t * 2] = i1; ti[t * 2 + 1] = i2;
    tw[t * 2] = v1 / sx; tw[t * 2 + 1] = v2 / sx;
  }
}

// ---------------- fused MoE-combine + LayerNorm (+ optional plane split) ----------------
__global__ __launch_bounds__(256) void k_ln_comb(
    const float* __restrict__ Xin, const float* __restrict__ Yb, int ldY,
    const int* __restrict__ slotmap, const float* __restrict__ tw,
    const float* __restrict__ sc, const float* __restrict__ bi, float* __restrict__ Y,
    unsigned short* __restrict__ oh, unsigned short* __restrict__ ol)
{
  int t = blockIdx.x, d = threadIdx.x;
  size_t idx = (size_t)t * 256 + d;
  int s0 = slotmap[2 * t], s1 = slotmap[2 * t + 1];
  float w0 = tw[2 * t], w1 = tw[2 * t + 1];
  float v = w0 * Yb[(size_t)s0 * ldY + d] + w1 * Yb[(size_t)s1 * ldY + d];
  if (Xin) v += Xin[idx];
  __shared__ float red[8];
  int lane = d & 63, wid = d >> 6;
  float s = v;
#pragma unroll
  for (int off = 32; off > 0; off >>= 1) s += __shfl_xor(s, off, 64);
  if (lane == 0) red[wid] = s;
  __syncthreads();
  float mean = (red[0] + red[1] + red[2] + red[3]) * 0.00390625f;
  float dv = v - mean;
  float s2 = dv * dv;
#pragma unroll
  for (int off = 32; off > 0; off >>= 1) s2 += __shfl_xor(s2, off, 64);
  if (lane == 0) red[4 + wid] = s2;
  __syncthreads();
  float var = (red[4] + red[5] + red[6] + red[7]) * 0.00390625f;
  float y = dv * (1.0f / sqrtf(var + 1e-5f)) * sc[d] + bi[d];
  Y[idx] = y;
  if (oh) {
    unsigned short hh, ll;
    bf16_split(y, hh, ll);
    oh[idx] = hh; ol[idx] = ll;
  }
}

// ---------------- count + 128-aligned scan + padding init ----------------
template <int E>
__global__ __launch_bounds__(256) void k_count_scan(
    const int* __restrict__ ti, int T,
    int* __restrict__ offs, int* __restrict__ cnt2, int* __restrict__ tok)
{
  __shared__ int sc[8];
  __shared__ int soffs[9];
  __shared__ int scnt[8];
  int tid = threadIdx.x;
  if (tid < 8) { sc[tid] = 0; cnt2[tid] = 0; }
  __syncthreads();
  int c[E];
#pragma unroll
  for (int k = 0; k < E; ++k) c[k] = 0;
  const int4* t4 = (const int4*)ti;
  for (int i = tid; i < (2 * T) >> 2; i += 256) {
    int4 v = t4[i];
#pragma unroll
    for (int k = 0; k < E; ++k) {
      c[k] += (v.x == k) ? 1 : 0;
      c[k] += (v.y == k) ? 1 : 0;
      c[k] += (v.z == k) ? 1 : 0;
      c[k] += (v.w == k) ? 1 : 0;
    }
  }
#pragma unroll
  for (int k = 0; k < E; ++k) {
    int v = c[k];
#pragma unroll
    for (int off = 32; off > 0; off >>= 1) v += __shfl_xor(v, off, 64);
    if ((tid & 63) == 0) atomicAdd(&sc[k], v);
  }
  __syncthreads();
  if (tid == 0) {
    int o = 0;
    for (int e = 0; e < E; ++e) {
      soffs[e] = o; scnt[e] = sc[e];
      o += (sc[e] + 127) & ~127;          // 128-aligned for MFMA tiles
    }
    soffs[E] = o;
  }
  __syncthreads();
  if (tid <= E) offs[tid] = soffs[tid];
  for (int e = 0; e < E; ++e) {
    int s0 = soffs[e] + scnt[e], s1 = soffs[e + 1];
    for (int i = s0 + tid; i < s1; i += 256) tok[i] = -1;
  }
}

// ---------------- fill expert slot lists + token->slot map ----------------
__global__ __launch_bounds__(256) void k_fill(
    const int* __restrict__ ti, int T,
    const int* __restrict__ offs, int* __restrict__ cnt2,
    int* __restrict__ tok, int* __restrict__ slotmap)
{
  __shared__ int lcnt[8];
  __shared__ int lbase[8];
  int tid = threadIdx.x;
  if (tid < 8) lcnt[tid] = 0;
  __syncthreads();
  int t = blockIdx.x * 256 + tid;
  int e0 = 0, e1 = 0, p0 = 0, p1 = 0;
  bool act = (t < T);
  if (act) {
    e0 = ti[t * 2]; e1 = ti[t * 2 + 1];
    p0 = atomicAdd(&lcnt[e0], 1);
    p1 = atomicAdd(&lcnt[e1], 1);
  }
  __syncthreads();
  if (tid < 8) lbase[tid] = atomicAdd(&cnt2[tid], lcnt[tid]);
  __syncthreads();
  if (act) {
    int s0 = offs[e0] + lbase[e0] + p0;
    tok[s0] = t; slotmap[t * 2] = s0;
    int s1 = offs[e1] + lbase[e1] + p1;
    tok[s1] = t; slotmap[t * 2 + 1] = s1;
  }
}

// ---------------- final logits ----------------
__global__ __launch_bounds__(256) void k_final(
    const float* __restrict__ FH, const float* __restrict__ w2,
    const float* __restrict__ b2, float* __restrict__ out, int T)
{
  int lane = threadIdx.x & 63, wid = threadIdx.x >> 6;
  int t = blockIdx.x * 4 + wid;
  if (t >= T) return;
  float4 h = *(const float4*)(FH + (size_t)t * 256 + lane * 4);
  float4 w = *(const float4*)(w2 + lane * 4);
  float s = h.x * w.x + h.y * w.y + h.z * w.z + h.w * w.w;
#pragma unroll
  for (int off = 32; off > 0; off >>= 1) s += __shfl_xor(s, off, 64);
  if (lane == 0) out[t] = s + b2[0];
}

// ---------------- aux load-balance loss ----------------
__global__ __launch_bounds__(256) void k_aux(
    const float* __restrict__ p0, const float* __restrict__ p1,
    const float* __restrict__ pi, float* __restrict__ out_aux)
{
  __shared__ float red[256];
  int tid = threadIdx.x;
  float aux = 0.f;
  for (int r = 0; r < 2; ++r) {
    const float* P = (r == 0) ? p0 : p1;
    float loc[4] = {0.f, 0.f, 0.f, 0.f};
    for (int t = tid; t < T_U; t += 256) {
#pragma unroll
      for (int e = 0; e < 4; ++e) loc[e] += P[t * 4 + e];
    }
    float contrib = 0.f;
    for (int e = 0; e < 4; ++e) {
      red[tid] = loc[e];
      __syncthreads();
      for (int s = 128; s > 0; s >>= 1) { if (tid < s) red[tid] += red[tid + s]; __syncthreads(); }
      if (tid == 0) { float d = red[0] * (1.f / T_U) - 0.125f; contrib += d * d; }
      __syncthreads();
    }
    if (tid == 0) aux += contrib * 0.25f;
  }
  {
    float loc[8] = {};
    for (int t = tid; t < T_I; t += 256) {
#pragma unroll
      for (int e = 0; e < 8; ++e) loc[e] += pi[t * 8 + e];
    }
    float contrib = 0.f;
    for (int e = 0; e < 8; ++e) {
      red[tid] = loc[e];
      __syncthreads();
      for (int s = 128; s > 0; s >>= 1) { if (tid < s) red[tid] += red[tid + s]; __syncthreads(); }
      if (tid == 0) { float d = red[0] * (1.f / T_I) - 0.125f; contrib += d * d; }
      __syncthreads();
    }
    if (tid == 0) aux += contrib * 0.125f;
  }
  if (tid == 0) *out_aux = aux;
}

// =======================================================================
extern "C" void kernel_launch(void* const* d_in, const int* in_sizes, int n_in,
                              void* d_out, int out_size, void* d_ws, size_t ws_size,
                              hipStream_t stream)
{
  (void)in_sizes; (void)n_in; (void)out_size;
  const int*   history  = (const int*)d_in[0];
  const int*   cand     = (const int*)d_in[1];
  const int*   catid    = (const int*)d_in[2];
  const float* item_emb = (const float*)d_in[3];
  const float* cat_emb  = (const float*)d_in[4];
  const float* ub_in_w  = (const float*)d_in[5];
  const float* ub_in_b  = (const float*)d_in[6];
  const float* ub_out_w = (const float*)d_in[7];
  const float* ub_out_b = (const float*)d_in[8];
  const float* ub_n1_s  = (const float*)d_in[9];
  const float* ub_n1_b  = (const float*)d_in[10];
  const float* ub_n2_s  = (const float*)d_in[11];
  const float* ub_n2_b  = (const float*)d_in[12];
  const float* ub_gate_w= (const float*)d_in[13];
  const float* ub_gate_b= (const float*)d_in[14];
  const float* ub_e_w1  = (const float*)d_in[15];
  const float* ub_e_b1  = (const float*)d_in[16];
  const float* ub_e_w2  = (const float*)d_in[17];
  const float* ub_e_b2  = (const float*)d_in[18];
  const float* un_s     = (const float*)d_in[19];
  const float* un_b     = (const float*)d_in[20];
  const float* im_gate_w= (const float*)d_in[21];
  const float* im_gate_b= (const float*)d_in[22];
  const float* im_e_w1  = (const float*)d_in[23];
  const float* im_e_b1  = (const float*)d_in[24];
  const float* im_e_w2  = (const float*)d_in[25];
  const float* im_e_b2  = (const float*)d_in[26];
  const float* in_s     = (const float*)d_in[27];
  const float* in_b     = (const float*)d_in[28];
  const float* ca_in_w  = (const float*)d_in[29];
  const float* ca_in_b  = (const float*)d_in[30];
  const float* ca_out_w = (const float*)d_in[31];
  const float* ca_out_b = (const float*)d_in[32];
  const float* fm_w1    = (const float*)d_in[33];
  const float* fm_b1    = (const float*)d_in[34];
  const float* fm_w2    = (const float*)d_in[35];
  const float* fm_b2    = (const float*)d_in[36];
  float* out = (float*)d_out;

  float* W = (float*)d_ws;
  size_t o = 0;
  auto alloc = [&](size_t n) { size_t r = o; o += (n + 63) & ~(size_t)63; return r; };
  const size_t oX    = alloc((size_t)T_U * 256);
  const size_t oQKV  = alloc((size_t)T_U * 768);   // region A (reuse: H planes / Kbuf,Vbuf)
  const size_t oAO   = alloc((size_t)T_U * 256);   // region B (H spillover)
  const size_t oEXT  = alloc(300000);              // region C (H tail)
  const size_t oTMP  = alloc((size_t)T_U * 256);
  const size_t oP0   = alloc((size_t)T_U * 4);
  const size_t oP1   = alloc((size_t)T_U * 4);
  const size_t oPI   = alloc((size_t)T_I * 8);
  const size_t oTW   = alloc((size_t)T_U * 2);
  const size_t oSM   = alloc((size_t)T_U * 2);     // int slotmap
  const size_t oTI   = alloc((size_t)T_U * 2);     // int
  const size_t oTOK  = alloc(CAP_U);               // int
  const size_t oCNT  = alloc(64);                  // int cnt2[8]|offs[9]
  const size_t oZERO = alloc(512);                 // 2KB zero region for gll pads
  const size_t oIE   = alloc((size_t)T_I * 256);
  const size_t oITEM = alloc((size_t)T_I * 256);
  const size_t oQB   = alloc((size_t)T_I * 256);
  const size_t oOB   = alloc((size_t)T_I * 256);
  const size_t oTAW  = alloc((size_t)T_I * 256);
  const size_t oFH   = alloc((size_t)T_I * 256);
  const size_t oWB   = alloc(4915200);             // bf16 weight arena: 2 planes x 4,915,200 shorts
  const size_t oCVT  = alloc((size_t)T_U * 256);   // activation hi/lo planes (user)
  const size_t oCVI  = alloc((size_t)T_I * 256);   // activation hi/lo planes (item)
  (void)oEXT;
  if (ws_size < o * sizeof(float)) {
    k_sentinel<<<1, 1, 0, stream>>>(out);
    return;
  }

  float* X    = W + oX;
  float* QKV  = W + oQKV;
  float* AO   = W + oAO;
  float* TMP  = W + oTMP;
  float* P0   = W + oP0;
  float* P1   = W + oP1;
  float* PI   = W + oPI;
  float* TWb  = W + oTW;
  int*   SLOT = (int*)(W + oSM);
  int*   TIb  = (int*)(W + oTI);
  int*   TOKb = (int*)(W + oTOK);
  int*   CNT  = (int*)(W + oCNT);
  int*   CNT2 = CNT;
  int*   OFFS = CNT + 8;
  const unsigned short* ZB = (const unsigned short*)(W + oZERO);
  float* IE   = W + oIE;
  float* ITEM = W + oITEM;
  float* QB   = W + oQB;
  float* OB   = W + oOB;
  float* TAW  = W + oTAW;
  float* FH   = W + oFH;
  float* Kbuf = QKV;
  float* Vbuf = QKV + (size_t)T_U * 256;
  (void)AO;

  // bf16 weight arena (per-plane short offsets)
  unsigned short* WH = (unsigned short*)(W + oWB);
  unsigned short* WL = WH + 4915200;
  const size_t off_in = 0, off_out = 393216, off_ew1 = 524288, off_ew2 = 1572864,
               off_iw1 = 2621440, off_iw2 = 3670016, off_ca = 4718592;
  // activation planes
  unsigned short* CVH = (unsigned short*)(W + oCVT);
  unsigned short* CVL = CVH + (size_t)T_U * 256;
  unsigned short* CIH = (unsigned short*)(W + oCVI);
  unsigned short* CIL = CIH + (size_t)T_I * 256;
  // H planes (user MoE) alias region A+B+C; Y fp32 aliases the Hlo plane.
  unsigned short* Hhi = (unsigned short*)(W + oQKV);
  unsigned short* Hlo = Hhi + (size_t)CAP_U * 512;
  float* Yu = (float*)Hlo;                          // CAP_U x 256 fp32
  unsigned short* iHhi = (unsigned short*)(W + oQKV);
  unsigned short* iHlo = iHhi + (size_t)CAP_I * 512;
  float* Yi = (float*)iHlo;                         // CAP_I x 256 fp32

  // 0) fused weight conversions + zero pad-source (1 launch)
  k_cvt_all<<<4800, 256, 0, stream>>>(ub_in_w, ub_out_w, ub_e_w1, ub_e_w2,
                                      im_e_w1, im_e_w2, ca_in_w, WH, WL, W + oZERO);

  // 1) embedding + rope (+ X planes)
  k_embed_rope<<<T_U, 256, 0, stream>>>(history, item_emb, X, CVH, CVL);

  // 2) user transformer layers
  for (int l = 0; l < 2; ++l) {
    k_mfmm<<<dim3(6, 100), 256, 0, stream>>>(CVH, CVL, nullptr, nullptr, 0,
        WH + off_in + (size_t)l * 196608, WL + off_in + (size_t)l * 196608,
        ub_in_b + l * 768, ZB, QKV, nullptr, nullptr, 768, 256, 768, 0);
    k_attn_mfma<<<512, 256, 0, stream>>>(QKV, CVH, CVL);
    k_mfmm<<<dim3(2, 100), 256, 0, stream>>>(CVH, CVL, nullptr, nullptr, 0,
        WH + off_out + (size_t)l * 65536, WL + off_out + (size_t)l * 65536,
        ub_out_b + l * 256, ZB, TMP, nullptr, nullptr, 256, 256, 256, 0);
    // n1 LN + planes + fused router<4>
    k_ln_router<4><<<T_U, 256, 0, stream>>>(X, TMP, ub_n1_s + l * 256, ub_n1_b + l * 256,
        X, CVH, CVL, ub_gate_w + (size_t)l * 4 * 256, ub_gate_b + l * 4,
        (l == 0) ? P0 : P1, TIb, TWb);
    k_count_scan<4><<<1, 256, 0, stream>>>(TIb, T_U, OFFS, CNT2, TOKb);
    k_fill<<<T_U / 256, 256, 0, stream>>>(TIb, T_U, OFFS, CNT2, TOKb, SLOT);
    k_mfmm<<<dim3(4, CAP_U / 128), 256, 0, stream>>>(CVH, CVL, TOKb, OFFS, 4,
        WH + off_ew1 + (size_t)l * 524288, WL + off_ew1 + (size_t)l * 524288,
        ub_e_b1 + (size_t)l * 2048, ZB, nullptr, Hhi, Hlo, 512, 256, 512, 1);
    k_mfmm_y<<<dim3(1, CAP_U / 64), 256, 0, stream>>>(Hhi, Hlo, OFFS, 4,
        WH + off_ew2 + (size_t)l * 524288, WL + off_ew2 + (size_t)l * 524288,
        ub_e_b2 + (size_t)l * 1024, Yu, 512);
    k_ln_comb<<<T_U, 256, 0, stream>>>(X, Yu, 256, SLOT, TWb,
        ub_n2_s + l * 256, ub_n2_b + l * 256, X,
        (l == 0) ? CVH : nullptr, (l == 0) ? CVL : nullptr);
  }

  // 3) history final LN (+ planes for xattn K/V projections)
  k_ln<<<T_U, 256, 0, stream>>>(X, nullptr, un_s, un_b, X, CVH, CVL);

  // 4) item tower (embed + planes + fused router<8>)
  k_item_embed_router<<<T_I, 256, 0, stream>>>(cand, catid, item_emb, cat_emb,
      IE, CIH, CIL, im_gate_w, im_gate_b, PI, TIb, TWb);
  k_count_scan<8><<<1, 256, 0, stream>>>(TIb, T_I, OFFS, CNT2, TOKb);
  k_fill<<<T_I / 256, 256, 0, stream>>>(TIb, T_I, OFFS, CNT2, TOKb, SLOT);
  k_mfmm<<<dim3(4, CAP_I / 128), 256, 0, stream>>>(CIH, CIL, TOKb, OFFS, 8,
      WH + off_iw1, WL + off_iw1, im_e_b1, ZB, nullptr, iHhi, iHlo, 512, 256, 512, 1);
  k_mfmm_y<<<dim3(1, CAP_I / 64), 256, 0, stream>>>(iHhi, iHlo, OFFS, 8,
      WH + off_iw2, WL + off_iw2, im_e_b2, Yi, 512);
  k_ln_comb<<<T_I, 256, 0, stream>>>(nullptr, Yi, 256, SLOT, TWb, in_s, in_b, ITEM,
                                     nullptr, nullptr);

  // 5) cross attention
  k_gemm<<<dim3(4, 16), 256, 0, stream>>>(ITEM, nullptr, ca_in_w, ca_in_b, QB,
                                          T_I, 256, 256, 0);
  k_mfmm<<<dim3(2, 100), 256, 0, stream>>>(CVH, CVL, nullptr, nullptr, 0,
      WH + off_ca + 65536, WL + off_ca + 65536, ca_in_b + 256,
      ZB, Kbuf, nullptr, nullptr, 256, 256, 256, 0);
  k_mfmm<<<dim3(2, 100), 256, 0, stream>>>(CVH, CVL, nullptr, nullptr, 0,
      WH + off_ca + 131072, WL + off_ca + 131072, ca_in_b + 512,
      ZB, Vbuf, nullptr, nullptr, 256, 256, 256, 0);
  k_xattn<<<512, 256, 0, stream>>>(QB, Kbuf, Vbuf, OB);
  k_gemm<<<dim3(4, 16), 256, 0, stream>>>(OB, nullptr, ca_out_w, ca_out_b, TAW,
                                          T_I, 256, 256, 0);

  // 6) fusion MLP (concat fused via dual-A) + logits
  k_gemm<<<dim3(4, 16), 256, 0, stream>>>(TAW, ITEM, fm_w1, fm_b1, FH,
                                          T_I, 256, 512, 1);
  k_final<<<T_I / 4, 256, 0, stream>>>(FH, fm_w2, fm_b2, out, T_I);

  // 7) aux loss
  k_aux<<<1, 256, 0, stream>>>(P0, P1, PI, out + 1024);
}

// Round 10
// 872.299 us; speedup vs baseline: 1.0138x; 1.0138x over previous
//
#include <hip/hip_runtime.h>
#include <cstddef>
#include <cstdint>

#define T_U   12800   // user tokens B*S
#define T_I   1024    // item tokens B*Nc
#define CAP_U 26112   // 2*T_U + 4*128 slot capacity (128-aligned per expert)
#define CAP_I 3072    // 2*T_I + 8*128

using short8 = __attribute__((ext_vector_type(8))) short;   // 8 bf16 (4 VGPRs)
using f32x4  = __attribute__((ext_vector_type(4))) float;

__device__ __forceinline__ float gelu_f(float x) {
  return 0.5f * x * (1.0f + erff(x * 0.7071067811865476f));
}

// split fp32 -> (hi, lo) bf16 with RNE; x ~= hi + lo to ~17 mantissa bits
__device__ __forceinline__ void bf16_split(float x, unsigned short& h, unsigned short& l) {
  unsigned int u = __float_as_uint(x);
  unsigned short hs = (unsigned short)((u + 0x7FFFu + ((u >> 16) & 1u)) >> 16);
  float hf = __uint_as_float(((unsigned int)hs) << 16);
  float r = x - hf;
  unsigned int u2 = __float_as_uint(r);
  unsigned short ls = (unsigned short)((u2 + 0x7FFFu + ((u2 >> 16) & 1u)) >> 16);
  h = hs; l = ls;
}

// pack 8 fp32 -> hi/lo short8 fragments (RNE split)
__device__ __forceinline__ void split8v(float4 a, float4 b, short8& h, short8& l) {
  unsigned short hh, ll;
  bf16_split(a.x, hh, ll); h[0] = (short)hh; l[0] = (short)ll;
  bf16_split(a.y, hh, ll); h[1] = (short)hh; l[1] = (short)ll;
  bf16_split(a.z, hh, ll); h[2] = (short)hh; l[2] = (short)ll;
  bf16_split(a.w, hh, ll); h[3] = (short)hh; l[3] = (short)ll;
  bf16_split(b.x, hh, ll); h[4] = (short)hh; l[4] = (short)ll;
  bf16_split(b.y, hh, ll); h[5] = (short)hh; l[5] = (short)ll;
  bf16_split(b.z, hh, ll); h[6] = (short)hh; l[6] = (short)ll;
  bf16_split(b.w, hh, ll); h[7] = (short)hh; l[7] = (short)ll;
}

// cheap truncation split for non-negative values (softmax P): ~2^-16 rel
__device__ __forceinline__ void psplit8(float4 a, float4 b, short8& h, short8& l) {
  unsigned int u; float x;
#define PS_(VAL, i)                                     \
  u = __float_as_uint(VAL);                             \
  h[i] = (short)(u >> 16);                              \
  x = (VAL) - __uint_as_float(u & 0xFFFF0000u);         \
  l[i] = (short)(__float_as_uint(x) >> 16);
  PS_(a.x, 0) PS_(a.y, 1) PS_(a.z, 2) PS_(a.w, 3)
  PS_(b.x, 4) PS_(b.y, 5) PS_(b.z, 6) PS_(b.w, 7)
#undef PS_
}

// async global->LDS, 16B per lane. LDS dest is wave-uniform base + lane*16.
__device__ __forceinline__ void gll16(const unsigned short* g, unsigned short* l) {
  __builtin_amdgcn_global_load_lds(
      (const __attribute__((address_space(1))) unsigned int*)g,
      (__attribute__((address_space(3))) unsigned int*)l, 16, 0, 0);
}

// bare s_barrier (no vmcnt drain) with compiler memory fence
__device__ __forceinline__ void wg_barrier() {
  asm volatile("" ::: "memory");
  __builtin_amdgcn_s_barrier();
  asm volatile("" ::: "memory");
}
// counted vmcnt waits (T4)
#define VMWAIT(N)                                              \
  do {                                                         \
    asm volatile("s_waitcnt vmcnt(" #N ")" ::: "memory");      \
    __builtin_amdgcn_sched_barrier(0);                         \
  } while (0)

#define FMA16(a, b, acc)                                                        \
  acc[0][0] += a.x * b.x; acc[0][1] += a.x * b.y; acc[0][2] += a.x * b.z; acc[0][3] += a.x * b.w; \
  acc[1][0] += a.y * b.x; acc[1][1] += a.y * b.y; acc[1][2] += a.y * b.z; acc[1][3] += a.y * b.w; \
  acc[2][0] += a.z * b.x; acc[2][1] += a.z * b.y; acc[2][2] += a.z * b.z; acc[2][3] += a.z * b.w; \
  acc[3][0] += a.w * b.x; acc[3][1] += a.w * b.y; acc[3][2] += a.w * b.z; acc[3][3] += a.w * b.w;

// ---------------- sentinel (ws too small) ----------------
__global__ void k_sentinel(float* out) { out[0] = 1.0e9f; }

// ---------------- fused weight cvt (all 7 tensors; arena is contiguous) ----------------
__global__ __launch_bounds__(256) void k_cvt_all(
    const float* __restrict__ s0, const float* __restrict__ s1,
    const float* __restrict__ s2, const float* __restrict__ s3,
    const float* __restrict__ s4, const float* __restrict__ s5,
    const float* __restrict__ s6,
    unsigned short* __restrict__ hi, unsigned short* __restrict__ lo,
    float* __restrict__ zb)
{
  int i = blockIdx.x * 256 + threadIdx.x;      // float4 index, < 1228800
  if (i < 512) zb[i] = 0.f;
  const float* src; int base;
  if (i < 131072)       { if (i < 98304)  { src = s0; base = 0; }       else { src = s1; base = 98304; } }
  else if (i < 655360)  { if (i < 393216) { src = s2; base = 131072; }  else { src = s3; base = 393216; } }
  else if (i < 1179648) { if (i < 917504) { src = s4; base = 655360; }  else { src = s5; base = 917504; } }
  else                  { src = s6; base = 1179648; }
  float4 v = ((const float4*)src)[i - base];
  ushort4 h, l;
  bf16_split(v.x, h.x, l.x);
  bf16_split(v.y, h.y, l.y);
  bf16_split(v.z, h.z, l.z);
  bf16_split(v.w, h.w, l.w);
  ((ushort4*)hi)[i] = h;
  ((ushort4*)lo)[i] = l;
}

// ---------------- embedding + (faithful) RoPE + fused plane split ----------------
__global__ __launch_bounds__(256) void k_embed_rope(
    const int* __restrict__ hist, const float* __restrict__ emb, float* __restrict__ X,
    unsigned short* __restrict__ XH, unsigned short* __restrict__ XL)
{
  int t = blockIdx.x;
  int s = t % 200;
  int d = threadIdx.x;
  const float* row = emb + (size_t)hist[t] * 256;
  float x0 = row[d];
  float x1 = row[(d + 1) & 255];
  int fi = d & 127;
  float inv = expf(-9.210340371976184f * ((float)fi * (1.0f / 128.0f)));
  float ang = (float)s * inv;
  float v = x0 * cosf(ang) + x1 * sinf(ang);
  size_t idx = (size_t)t * 256 + d;
  X[idx] = v;
  unsigned short hh, ll;
  bf16_split(v, hh, ll);
  XH[idx] = hh; XL[idx] = ll;
}

// ---------------- item embedding sum + plane split + fused router<8> ----------------
__global__ __launch_bounds__(256) void k_item_embed_router(
    const int* __restrict__ cand, const int* __restrict__ catid,
    const float* __restrict__ item_emb, const float* __restrict__ cat_emb,
    float* __restrict__ IE, unsigned short* __restrict__ IH, unsigned short* __restrict__ IL,
    const float* __restrict__ gw, const float* __restrict__ gb,
    float* __restrict__ probs, int* __restrict__ ti, float* __restrict__ tw)
{
  const int E = 8;
  int t = blockIdx.x, d = threadIdx.x;
  float v = item_emb[(size_t)cand[t] * 256 + d] + cat_emb[(size_t)catid[t] * 256 + d];
  size_t idx = (size_t)t * 256 + d;
  IE[idx] = v;
  unsigned short hh, ll;
  bf16_split(v, hh, ll);
  IH[idx] = hh; IL[idx] = ll;
  __shared__ float redg[32];
  int lane = d & 63, wid = d >> 6;
#pragma unroll
  for (int e = 0; e < E; ++e) {
    float s = v * gw[e * 256 + d];
#pragma unroll
    for (int off = 32; off > 0; off >>= 1) s += __shfl_xor(s, off, 64);
    if (lane == 0) redg[wid * E + e] = s;
  }
  __syncthreads();
  if (d == 0) {
    float p[E];
    float m = -1e30f;
#pragma unroll
    for (int e = 0; e < E; ++e) {
      p[e] = redg[e] + redg[E + e] + redg[2 * E + e] + redg[3 * E + e] + gb[e];
      m = fmaxf(m, p[e]);
    }
    float sum = 0.f;
#pragma unroll
    for (int e = 0; e < E; ++e) { p[e] = expf(p[e] - m); sum += p[e]; }
    float inv = 1.f / sum;
#pragma unroll
    for (int e = 0; e < E; ++e) { p[e] *= inv; probs[(size_t)t * E + e] = p[e]; }
    float v1 = p[0]; int i1 = 0;
#pragma unroll
    for (int e = 1; e < E; ++e) if (p[e] > v1) { v1 = p[e]; i1 = e; }
    float v2 = -1.f; int i2 = 0;
#pragma unroll
    for (int e = 0; e < E; ++e) if (e != i1 && p[e] > v2) { v2 = p[e]; i2 = e; }
    float s2 = v1 + v2;
    ti[t * 2] = i1; ti[t * 2 + 1] = i2;
    tw[t * 2] = v1 / s2; tw[t * 2 + 1] = v2 / s2;
  }
}

// ---------------- fp32 GEMM (tiny T_I matmuls); optional dual-A (concat fusion) ----------------
__global__ __launch_bounds__(256) void k_gemm(
    const float* __restrict__ A, const float* __restrict__ A2,
    const float* __restrict__ Wm,
    const float* __restrict__ bias, float* __restrict__ C,
    int M, int N, int K, int act)
{
  __shared__ float As[16][68];
  __shared__ float Ws[16][68];
  int tid = threadIdx.x;
  int row0 = blockIdx.y << 6;
  int col0 = blockIdx.x << 6;
  int lr = tid >> 2, lk = (tid & 3) << 2;
  int tx = tid & 15, ty = tid >> 4;
  const float* Wload = Wm + (size_t)(col0 + lr) * K + lk;
  float acc[4][4] = {};
  for (int k0 = 0; k0 < K; k0 += 16) {
    int kk = k0 + lk;
    const float* ap;
    if (A2) ap = (kk < 256) ? A + (size_t)(row0 + lr) * 256 + kk
                            : A2 + (size_t)(row0 + lr) * 256 + (kk - 256);
    else    ap = A + (size_t)(row0 + lr) * K + kk;
    float4 av = *(const float4*)ap;
    float4 wv = *(const float4*)(Wload + k0);
    As[lk][lr] = av.x; As[lk + 1][lr] = av.y; As[lk + 2][lr] = av.z; As[lk + 3][lr] = av.w;
    Ws[lk][lr] = wv.x; Ws[lk + 1][lr] = wv.y; Ws[lk + 2][lr] = wv.z; Ws[lk + 3][lr] = wv.w;
    __syncthreads();
#pragma unroll
    for (int k = 0; k < 16; ++k) {
      float4 a = *(const float4*)&As[k][ty << 2];
      float4 b = *(const float4*)&Ws[k][tx << 2];
      FMA16(a, b, acc);
    }
    __syncthreads();
  }
#pragma unroll
  for (int i = 0; i < 4; ++i) {
    int r = row0 + (ty << 2) + i;
    int c0 = col0 + (tx << 2);
    float4 v;
    v.x = acc[i][0]; v.y = acc[i][1]; v.z = acc[i][2]; v.w = acc[i][3];
    if (bias) { v.x += bias[c0]; v.y += bias[c0 + 1]; v.z += bias[c0 + 2]; v.w += bias[c0 + 3]; }
    if (act) { v.x = gelu_f(v.x); v.y = gelu_f(v.y); v.z = gelu_f(v.z); v.w = gelu_f(v.w); }
    *(float4*)(C + (size_t)r * N + c0) = v;
  }
}

// ---------------- MFMA GEMM, split-bf16 (3-product), 128x128 tile ----------------
// gll staging, double-buffered LDS, T4 counted-vmcnt pipeline.
// T1 XCD swizzle: contiguous y-chunks per XCD (A-panel L2 locality);
// bijective when gridDim.x*gridDim.y % 8 == 0 (all our grids are).
__global__ __launch_bounds__(256, 2) void k_mfmm(
    const unsigned short* __restrict__ Ahi, const unsigned short* __restrict__ Alo,
    const int* __restrict__ tok, const int* __restrict__ offs, int E,
    const unsigned short* __restrict__ Whi, const unsigned short* __restrict__ Wlo,
    const float* __restrict__ bias, const unsigned short* __restrict__ zbuf,
    float* __restrict__ OutF, unsigned short* __restrict__ OutHi,
    unsigned short* __restrict__ OutLo,
    int N, int K, int ldOut, int act)
{
  // ---- T1 XCD-aware block swizzle ----
  int nwg = gridDim.x * gridDim.y;
  int lin = blockIdx.y * gridDim.x + blockIdx.x;
  int idx = ((nwg & 7) == 0) ? ((lin & 7) * (nwg >> 3) + (lin >> 3)) : lin;
  int by = idx / gridDim.x, bx = idx - by * gridDim.x;

  int row0 = by << 7;
  const float* bp = bias;
  const unsigned short* Wh = Whi;
  const unsigned short* Wl = Wlo;
  if (offs) {
    if (row0 >= offs[E]) return;
    int e = E - 1;
    while (e > 0 && offs[e] > row0) --e;
    Wh += (size_t)e * N * K;
    Wl += (size_t)e * N * K;
    bp += (size_t)e * N;
  }
  int col0 = bx << 7;
  __shared__ __align__(16) unsigned short smem[32768];   // 64 KB
  unsigned short* sA = smem;            // 2 bufs x 8192 shorts
  unsigned short* sW = smem + 16384;    // 2 bufs x 8192 shorts
  int tid = threadIdx.x, lane = tid & 63, w = tid >> 6;

  const unsigned short* srcA[4];
  const unsigned short* srcW[4];
  int ldsOff[4];
  {
    int rsub = lane >> 3, c = lane & 7;
#pragma unroll
    for (int j = 0; j < 4; ++j) {
      int q = w * 4 + j;
      int r = q * 8 + rsub;                 // 0..127
      int lc = c ^ (r & 7);                 // logical chunk stored here
      const unsigned short *ph, *pl;
      if (tok) {
        int t = tok[row0 + r];
        if (t < 0) { ph = zbuf; pl = zbuf; }
        else { ph = Ahi + (size_t)t * K; pl = Alo + (size_t)t * K; }
      } else {
        ph = Ahi + (size_t)(row0 + r) * K;
        pl = Alo + (size_t)(row0 + r) * K;
      }
      srcA[j] = (lc < 4) ? (ph + lc * 8) : (pl + (lc - 4) * 8);
      const unsigned short* wh = Wh + (size_t)(col0 + r) * K;
      const unsigned short* wl = Wl + (size_t)(col0 + r) * K;
      srcW[j] = (lc < 4) ? (wh + lc * 8) : (wl + (lc - 4) * 8);
      ldsOff[j] = q * 512;                  // shorts; wave-uniform
    }
  }

  int wv = w, fr = lane & 15, g = lane >> 4;
  int wr = (wv & 1) << 6, wc = (wv >> 1) << 6;
  int swh = (g ^ (fr & 7)) * 8;             // phys offset of hi chunk g (shorts)
  int swl = ((g | 4) ^ (fr & 7)) * 8;       // phys offset of lo chunk g

  f32x4 acc[4][4] = {};

  auto STAGE = [&](int buf, int k0) {
    unsigned short* a = sA + buf * 8192;
    unsigned short* b = sW + buf * 8192;
#pragma unroll
    for (int j = 0; j < 4; ++j) {
      gll16(srcA[j] + k0, a + ldsOff[j]);
      gll16(srcW[j] + k0, b + ldsOff[j]);
    }
  };
  auto COMPUTE = [&](int buf) {
    const unsigned short* a = sA + buf * 8192;
    const unsigned short* b = sW + buf * 8192;
    short8 ah[4], al[4], bh[4], bl[4];
#pragma unroll
    for (int mi = 0; mi < 4; ++mi) {
      int ro = (wr + mi * 16 + fr) * 64;
      ah[mi] = *(const short8*)(a + ro + swh);
      al[mi] = *(const short8*)(a + ro + swl);
    }
#pragma unroll
    for (int ni = 0; ni < 4; ++ni) {
      int ro = (wc + ni * 16 + fr) * 64;
      bh[ni] = *(const short8*)(b + ro + swh);
      bl[ni] = *(const short8*)(b + ro + swl);
    }
#pragma unroll
    for (int mi = 0; mi < 4; ++mi) {
#pragma unroll
      for (int ni = 0; ni < 4; ++ni) {
        acc[mi][ni] = __builtin_amdgcn_mfma_f32_16x16x32_bf16(ah[mi], bh[ni], acc[mi][ni], 0, 0, 0);
        acc[mi][ni] = __builtin_amdgcn_mfma_f32_16x16x32_bf16(ah[mi], bl[ni], acc[mi][ni], 0, 0, 0);
        acc[mi][ni] = __builtin_amdgcn_mfma_f32_16x16x32_bf16(al[mi], bh[ni], acc[mi][ni], 0, 0, 0);
      }
    }
  };

  int steps = K >> 5;
  STAGE(0, 0);
  for (int s = 0; s < steps; ++s) {
    bool more = (s + 1 < steps);
    if (more) STAGE((s + 1) & 1, (s + 1) << 5);   // +8 in flight
    if (more) VMWAIT(8); else VMWAIT(0);          // wait buf-s only
    wg_barrier();                                 // buf-s visible to all
    COMPUTE(s & 1);
    wg_barrier();                                 // read-join before overwrite
  }

  // ---- epilogue via LDS bounce (coalesced full-line stores) ----
  int fr4 = g << 2;
  if (OutF) {
    float* eo = (float*)smem;                 // [128][128] fp32 (64 KB)
#pragma unroll
    for (int ni = 0; ni < 4; ++ni) {
      int c = wc + ni * 16 + fr;
      float bv = bp[col0 + c];
#pragma unroll
      for (int mi = 0; mi < 4; ++mi) {
#pragma unroll
        for (int r = 0; r < 4; ++r) {
          float v = acc[mi][ni][r] + bv;
          if (act) v = gelu_f(v);
          eo[(wr + mi * 16 + fr4 + r) * 128 + c] = v;
        }
      }
    }
    __syncthreads();
#pragma unroll
    for (int i = 0; i < 16; ++i) {
      int ci = i * 256 + tid;                 // 4096 chunks of 16B
      int rr = ci >> 5, cc = ci & 31;
      float4 v = *(const float4*)(eo + rr * 128 + cc * 4);
      *(float4*)(OutF + (size_t)(row0 + rr) * ldOut + col0 + cc * 4) = v;
    }
  } else {
    unsigned short* eh = smem;                // [128][128] hi plane
    unsigned short* el = smem + 16384;        // [128][128] lo plane
#pragma unroll
    for (int ni = 0; ni < 4; ++ni) {
      int c = wc + ni * 16 + fr;
      float bv = bp[col0 + c];
#pragma unroll
      for (int mi = 0; mi < 4; ++mi) {
#pragma unroll
        for (int r = 0; r < 4; ++r) {
          float v = acc[mi][ni][r] + bv;
          if (act) v = gelu_f(v);
          unsigned short h, l;
          bf16_split(v, h, l);
          int o2 = (wr + mi * 16 + fr4 + r) * 128 + c;
          eh[o2] = h; el[o2] = l;
        }
      }
    }
    __syncthreads();
#pragma unroll
    for (int i = 0; i < 8; ++i) {
      int ci = i * 256 + tid;                 // 2048 chunks of 16B per plane
      int rr = ci >> 4, cc = ci & 15;
      uint4 vh = *(const uint4*)(eh + rr * 128 + cc * 8);
      uint4 vl = *(const uint4*)(el + rr * 128 + cc * 8);
      *(uint4*)(OutHi + (size_t)(row0 + rr) * ldOut + col0 + cc * 8) = vh;
      *(uint4*)(OutLo + (size_t)(row0 + rr) * ldOut + col0 + cc * 8) = vl;
    }
  }
}

// ---------------- MFMA GEMM variant: 64 rows x 256 cols per block ----------------
// Sole reader+writer of its rows. T1 XCD swizzle on y (W/expert locality).
__global__ __launch_bounds__(256, 2) void k_mfmm_y(
    const unsigned short* __restrict__ Ahi, const unsigned short* __restrict__ Alo,
    const int* __restrict__ offs, int E,
    const unsigned short* __restrict__ Whi, const unsigned short* __restrict__ Wlo,
    const float* __restrict__ bias, float* __restrict__ OutF, int K)
{
  const int N = 256;
  int nwg = gridDim.y;
  int lin = blockIdx.y;
  int by = ((nwg & 7) == 0) ? ((lin & 7) * (nwg >> 3) + (lin >> 3)) : lin;
  int row0 = by << 6;
  if (row0 >= offs[E]) return;
  int e = E - 1;
  while (e > 0 && offs[e] > row0) --e;
  const unsigned short* Wh = Whi + (size_t)e * N * K;
  const unsigned short* Wl = Wlo + (size_t)e * N * K;
  const float* bp = bias + (size_t)e * N;
  __shared__ __align__(16) unsigned short smem[40960];   // 80 KB
  unsigned short* sA = smem;            // 2 bufs x 4096 shorts (16 KB)
  unsigned short* sW = smem + 8192;     // 2 bufs x 16384 shorts (64 KB)
  int tid = threadIdx.x, lane = tid & 63, w = tid >> 6;

  const unsigned short* srcA[2];
  const unsigned short* srcW[8];
  int ldsAOff[2], ldsWOff[8];
  {
    int rsub = lane >> 3, c = lane & 7;
#pragma unroll
    for (int j = 0; j < 2; ++j) {
      int q = w * 2 + j;
      int r = q * 8 + rsub;                 // 0..63
      int lc = c ^ (r & 7);
      const unsigned short* ph = Ahi + (size_t)(row0 + r) * K;
      const unsigned short* pl = Alo + (size_t)(row0 + r) * K;
      srcA[j] = (lc < 4) ? (ph + lc * 8) : (pl + (lc - 4) * 8);
      ldsAOff[j] = q * 512;
    }
#pragma unroll
    for (int j = 0; j < 8; ++j) {
      int q = w * 8 + j;
      int r = q * 8 + rsub;                 // 0..255
      int lc = c ^ (r & 7);
      const unsigned short* wh = Wh + (size_t)r * K;
      const unsigned short* wl = Wl + (size_t)r * K;
      srcW[j] = (lc < 4) ? (wh + lc * 8) : (wl + (lc - 4) * 8);
      ldsWOff[j] = q * 512;
    }
  }

  int fr = lane & 15, g = lane >> 4;
  int wc = w << 6;                          // wave covers cols [wc, wc+64)
  int swh = (g ^ (fr & 7)) * 8;
  int swl = ((g | 4) ^ (fr & 7)) * 8;

  f32x4 acc[4][4] = {};

  auto STAGE = [&](int buf, int k0) {
    unsigned short* a = sA + buf * 4096;
    unsigned short* b = sW + buf * 16384;
#pragma unroll
    for (int j = 0; j < 2; ++j) gll16(srcA[j] + k0, a + ldsAOff[j]);
#pragma unroll
    for (int j = 0; j < 8; ++j) gll16(srcW[j] + k0, b + ldsWOff[j]);
  };
  auto COMPUTE = [&](int buf) {
    const unsigned short* a = sA + buf * 4096;
    const unsigned short* b = sW + buf * 16384;
    short8 ah[4], al[4], bh[4], bl[4];
#pragma unroll
    for (int mi = 0; mi < 4; ++mi) {
      int ro = (mi * 16 + fr) * 64;
      ah[mi] = *(const short8*)(a + ro + swh);
      al[mi] = *(const short8*)(a + ro + swl);
    }
#pragma unroll
    for (int ni = 0; ni < 4; ++ni) {
      int ro = (wc + ni * 16 + fr) * 64;
      bh[ni] = *(const short8*)(b + ro + swh);
      bl[ni] = *(const short8*)(b + ro + swl);
    }
#pragma unroll
    for (int mi = 0; mi < 4; ++mi) {
#pragma unroll
      for (int ni = 0; ni < 4; ++ni) {
        acc[mi][ni] = __builtin_amdgcn_mfma_f32_16x16x32_bf16(ah[mi], bh[ni], acc[mi][ni], 0, 0, 0);
        acc[mi][ni] = __builtin_amdgcn_mfma_f32_16x16x32_bf16(ah[mi], bl[ni], acc[mi][ni], 0, 0, 0);
        acc[mi][ni] = __builtin_amdgcn_mfma_f32_16x16x32_bf16(al[mi], bh[ni], acc[mi][ni], 0, 0, 0);
      }
    }
  };

  int steps = K >> 5;
  STAGE(0, 0);
  for (int s = 0; s < steps; ++s) {
    bool more = (s + 1 < steps);
    if (more) STAGE((s + 1) & 1, (s + 1) << 5);   // +10 in flight
    if (more) VMWAIT(10); else VMWAIT(0);         // wait buf-s only
    wg_barrier();
    COMPUTE(s & 1);
    wg_barrier();
  }

  // ---- epilogue via LDS bounce ----
  int fr4 = g << 2;
  float* eo = (float*)(smem + 8192);        // [64][256] fp32 (64 KB, over sW)
#pragma unroll
  for (int ni = 0; ni < 4; ++ni) {
    int c = wc + ni * 16 + fr;
    float bv = bp[c];
#pragma unroll
    for (int mi = 0; mi < 4; ++mi) {
#pragma unroll
      for (int r = 0; r < 4; ++r) {
        eo[(mi * 16 + fr4 + r) * 256 + c] = acc[mi][ni][r] + bv;
      }
    }
  }
  __syncthreads();
#pragma unroll
  for (int i = 0; i < 16; ++i) {
    int ci = i * 256 + tid;                 // 4096 chunks of 16B
    int rr = ci >> 6, cc = ci & 63;
    float4 v = *(const float4*)(eo + rr * 256 + cc * 4);
    *(float4*)(OutF + (size_t)(row0 + rr) * 256 + cc * 4) = v;
  }
}

// ---------------- self-attention via MFMA (split-bf16, per-wave q-tiles) ----------------
#define ATT_LDK 40    // shorts: 80B rows, 16B-aligned, <=2-way bank alias
#define ATT_LDV 216   // shorts: 432B rows, 16B-aligned, <=2-way
#define ATT_LDP 212   // floats: 848B rows, 16B-aligned, <=2-way
__global__ __launch_bounds__(256) void k_attn_mfma(
    const float* __restrict__ qkv,
    unsigned short* __restrict__ aoh, unsigned short* __restrict__ aol)
{
  __shared__ unsigned short sKh[208 * ATT_LDK];
  __shared__ unsigned short sKl[208 * ATT_LDK];
  __shared__ unsigned short sVh[32 * ATT_LDV];
  __shared__ unsigned short sVl[32 * ATT_LDV];
  __shared__ float sP[4 * 16 * ATT_LDP];
  int bh = blockIdx.x;
  int b = bh >> 3, h = bh & 7;
  const float* base = qkv + (size_t)b * 200 * 768 + h * 32;
  int tid = threadIdx.x;
  for (int i = tid; i < 1600; i += 256) {
    int s = i >> 3, d4 = (i & 7) << 2;
    float4 kv = *(const float4*)(base + (size_t)s * 768 + 256 + d4);
    float4 vv = *(const float4*)(base + (size_t)s * 768 + 512 + d4);
    ushort4 kh, kl;
    bf16_split(kv.x, kh.x, kl.x);
    bf16_split(kv.y, kh.y, kl.y);
    bf16_split(kv.z, kh.z, kl.z);
    bf16_split(kv.w, kh.w, kl.w);
    *(ushort4*)(sKh + s * ATT_LDK + d4) = kh;
    *(ushort4*)(sKl + s * ATT_LDK + d4) = kl;
    unsigned short vh, vl;
    bf16_split(vv.x, vh, vl); sVh[(d4 + 0) * ATT_LDV + s] = vh; sVl[(d4 + 0) * ATT_LDV + s] = vl;
    bf16_split(vv.y, vh, vl); sVh[(d4 + 1) * ATT_LDV + s] = vh; sVl[(d4 + 1) * ATT_LDV + s] = vl;
    bf16_split(vv.z, vh, vl); sVh[(d4 + 2) * ATT_LDV + s] = vh; sVl[(d4 + 2) * ATT_LDV + s] = vl;
    bf16_split(vv.w, vh, vl); sVh[(d4 + 3) * ATT_LDV + s] = vh; sVl[(d4 + 3) * ATT_LDV + s] = vl;
  }
  for (int i = tid; i < 8 * ATT_LDK; i += 256) {
    sKh[200 * ATT_LDK + i] = 0; sKl[200 * ATT_LDK + i] = 0;
  }
  for (int i = tid; i < 32 * 16; i += 256) {
    int d = i >> 4, c = 200 + (i & 15);
    sVh[d * ATT_LDV + c] = 0; sVl[d * ATT_LDV + c] = 0;
  }
  __syncthreads();

  int wv = tid >> 6, lane = tid & 63;
  int g = lane >> 4, fr = lane & 15;
  float* Pf = sP + wv * (16 * ATT_LDP);
  const float scale = 0.17677669529663687f;

  for (int t = wv; t < 13; t += 4) {
    int qbase = t << 4;
    int qrow = qbase + fr; if (qrow > 199) qrow = 199;
    const float* qp = base + (size_t)qrow * 768 + g * 8;
    float4 q0 = *(const float4*)qp;
    float4 q1 = *(const float4*)(qp + 4);
    short8 qah, qal;
    split8v(q0, q1, qah, qal);
    f32x4 acc[13] = {};
#pragma unroll
    for (int st = 0; st < 13; ++st) {
      int a = (st * 16 + fr) * ATT_LDK + g * 8;
      short8 bh = *(const short8*)(sKh + a);
      short8 bl = *(const short8*)(sKl + a);
      acc[st] = __builtin_amdgcn_mfma_f32_16x16x32_bf16(qah, bh, acc[st], 0, 0, 0);
      acc[st] = __builtin_amdgcn_mfma_f32_16x16x32_bf16(qah, bl, acc[st], 0, 0, 0);
      acc[st] = __builtin_amdgcn_mfma_f32_16x16x32_bf16(qal, bh, acc[st], 0, 0, 0);
    }
    float m[4] = {-1e30f, -1e30f, -1e30f, -1e30f};
#pragma unroll
    for (int st = 0; st < 13; ++st) {
      bool ok = (st * 16 + fr) < 200;
#pragma unroll
      for (int r = 0; r < 4; ++r) {
        float v = ok ? acc[st][r] * scale : -1e30f;
        acc[st][r] = v;
        m[r] = fmaxf(m[r], v);
      }
    }
#pragma unroll
    for (int r = 0; r < 4; ++r) {
      m[r] = fmaxf(m[r], __shfl_xor(m[r], 1, 64));
      m[r] = fmaxf(m[r], __shfl_xor(m[r], 2, 64));
      m[r] = fmaxf(m[r], __shfl_xor(m[r], 4, 64));
      m[r] = fmaxf(m[r], __shfl_xor(m[r], 8, 64));
    }
    float sum[4] = {0.f, 0.f, 0.f, 0.f};
#pragma unroll
    for (int st = 0; st < 13; ++st) {
      int scol = st * 16 + fr;
      bool ok = scol < 200;
#pragma unroll
      for (int r = 0; r < 4; ++r) {
        float e = ok ? __expf(acc[st][r] - m[r]) : 0.f;
        sum[r] += e;
        Pf[(g * 4 + r) * ATT_LDP + scol] = e;
      }
    }
#pragma unroll
    for (int r = 0; r < 4; ++r) {
      sum[r] += __shfl_xor(sum[r], 1, 64);
      sum[r] += __shfl_xor(sum[r], 2, 64);
      sum[r] += __shfl_xor(sum[r], 4, 64);
      sum[r] += __shfl_xor(sum[r], 8, 64);
      sum[r] = 1.f / sum[r];
    }
    f32x4 o00 = {}, o01 = {}, o10 = {}, o11 = {};
#pragma unroll
    for (int ks = 0; ks < 7; ++ks) {
      short8 pah = {}, pal = {}, v0h = {}, v0l = {}, v1h = {}, v1l = {};
      if (ks < 6 || g < 2) {
        const float* pr = Pf + fr * ATT_LDP + ks * 32 + g * 8;
        float4 p0 = *(const float4*)pr;
        float4 p1 = *(const float4*)(pr + 4);
        psplit8(p0, p1, pah, pal);
        int ko = ks * 32 + g * 8;
        v0h = *(const short8*)(sVh + fr * ATT_LDV + ko);
        v0l = *(const short8*)(sVl + fr * ATT_LDV + ko);
        v1h = *(const short8*)(sVh + (16 + fr) * ATT_LDV + ko);
        v1l = *(const short8*)(sVl + (16 + fr) * ATT_LDV + ko);
      }
      if (ks & 1) {
        o01 = __builtin_amdgcn_mfma_f32_16x16x32_bf16(pah, v0h, o01, 0, 0, 0);
        o01 = __builtin_amdgcn_mfma_f32_16x16x32_bf16(pah, v0l, o01, 0, 0, 0);
        o01 = __builtin_amdgcn_mfma_f32_16x16x32_bf16(pal, v0h, o01, 0, 0, 0);
        o11 = __builtin_amdgcn_mfma_f32_16x16x32_bf16(pah, v1h, o11, 0, 0, 0);
        o11 = __builtin_amdgcn_mfma_f32_16x16x32_bf16(pah, v1l, o11, 0, 0, 0);
        o11 = __builtin_amdgcn_mfma_f32_16x16x32_bf16(pal, v1h, o11, 0, 0, 0);
      } else {
        o00 = __builtin_amdgcn_mfma_f32_16x16x32_bf16(pah, v0h, o00, 0, 0, 0);
        o00 = __builtin_amdgcn_mfma_f32_16x16x32_bf16(pah, v0l, o00, 0, 0, 0);
        o00 = __builtin_amdgcn_mfma_f32_16x16x32_bf16(pal, v0h, o00, 0, 0, 0);
        o10 = __builtin_amdgcn_mfma_f32_16x16x32_bf16(pah, v1h, o10, 0, 0, 0);
        o10 = __builtin_amdgcn_mfma_f32_16x16x32_bf16(pah, v1l, o10, 0, 0, 0);
        o10 = __builtin_amdgcn_mfma_f32_16x16x32_bf16(pal, v1h, o10, 0, 0, 0);
      }
    }
#pragma unroll
    for (int r = 0; r < 4; ++r) {
      int qr = qbase + g * 4 + r;
      if (qr < 200) {
        size_t ob = (size_t)(b * 200 + qr) * 256 + h * 32;
        unsigned short hh, ll;
        bf16_split((o00[r] + o01[r]) * sum[r], hh, ll);
        aoh[ob + fr] = hh;      aol[ob + fr] = ll;
        bf16_split((o10[r] + o11[r]) * sum[r], hh, ll);
        aoh[ob + 16 + fr] = hh; aol[ob + 16 + fr] = ll;
      }
    }
  }
}

// ---------------- cross-attention ----------------
__global__ __launch_bounds__(256) void k_xattn(
    const float* __restrict__ Q, const float* __restrict__ Kb,
    const float* __restrict__ Vb, float* __restrict__ O)
{
  __shared__ float4 Ks[200 * 9];
  __shared__ float4 Vs[200 * 9];
  __shared__ float4 Qs[16 * 9];
  __shared__ float  Sc[16 * 209];
  __shared__ float  red[16 * 16];
  __shared__ float  mq_s[16], linv_s[16];
  int bh = blockIdx.x;
  int b = bh >> 3, h = bh & 7;
  int tid = threadIdx.x;
  for (int i = tid; i < 1600; i += 256) {
    int s = i >> 3, d = i & 7;
    Ks[s * 9 + d] = *(const float4*)(Kb + (size_t)(b * 200 + s) * 256 + h * 32 + d * 4);
    Vs[s * 9 + d] = *(const float4*)(Vb + (size_t)(b * 200 + s) * 256 + h * 32 + d * 4);
  }
  if (tid < 128) {
    int q = tid >> 3, d = tid & 7;
    Qs[q * 9 + d] = *(const float4*)(Q + (size_t)(b * 16 + q) * 256 + h * 32 + d * 4);
  }
  __syncthreads();
  const float scale = 0.17677669529663687f;
  int q = tid >> 4, si = tid & 15;
  float4 qr[8];
#pragma unroll
  for (int d = 0; d < 8; ++d) qr[d] = Qs[q * 9 + d];
  float sc[13];
  float lm = -1e30f;
#pragma unroll
  for (int j = 0; j < 13; ++j) {
    int s = si + 16 * j;
    if (s < 200) {
      float acc = 0.f;
#pragma unroll
      for (int d = 0; d < 8; ++d) {
        float4 kk = Ks[s * 9 + d];
        acc += qr[d].x * kk.x + qr[d].y * kk.y + qr[d].z * kk.z + qr[d].w * kk.w;
      }
      float v = acc * scale;
      sc[j] = v;
      lm = fmaxf(lm, v);
    }
  }
  red[q * 16 + si] = lm;
  __syncthreads();
  if (tid < 16) {
    float m = red[tid * 16];
#pragma unroll
    for (int k = 1; k < 16; ++k) m = fmaxf(m, red[tid * 16 + k]);
    mq_s[tid] = m;
  }
  __syncthreads();
  float mq = mq_s[q];
  float ls = 0.f;
#pragma unroll
  for (int j = 0; j < 13; ++j) {
    int s = si + 16 * j;
    if (s < 200) {
      float e = expf(sc[j] - mq);
      Sc[q * 209 + s] = e;
      ls += e;
    }
  }
  red[q * 16 + si] = ls;
  __syncthreads();
  if (tid < 16) {
    float s = 0.f;
#pragma unroll
    for (int k = 0; k < 16; ++k) s += red[tid * 16 + k];
    linv_s[tid] = 1.f / s;
  }
  __syncthreads();
  if (tid < 128) {
    int qq = tid >> 3, dd = tid & 7;
    float4 o = make_float4(0.f, 0.f, 0.f, 0.f);
    const float* prow = &Sc[qq * 209];
    for (int s = 0; s < 200; ++s) {
      float p = prow[s];
      float4 vv = Vs[s * 9 + dd];
      o.x += p * vv.x; o.y += p * vv.y; o.z += p * vv.z; o.w += p * vv.w;
    }
    float inv = linv_s[qq];
    o.x *= inv; o.y *= inv; o.z *= inv; o.w *= inv;
    *(float4*)(O + (size_t)(b * 16 + qq) * 256 + h * 32 + dd * 4) = o;
  }
}

// ---------------- LayerNorm (optional residual, optional fused plane split) ----------------
__global__ __launch_bounds__(256) void k_ln(
    const float* __restrict__ Xin, const float* __restrict__ R,
    const float* __restrict__ sc, const float* __restrict__ bi, float* __restrict__ Y,
    unsigned short* __restrict__ oh, unsigned short* __restrict__ ol)
{
  int t = blockIdx.x, d = threadIdx.x;
  size_t idx = (size_t)t * 256 + d;
  float v = Xin[idx];
  if (R) v += R[idx];
  __shared__ float red[8];
  int lane = d & 63, wid = d >> 6;
  float s = v;
#pragma unroll
  for (int off = 32; off > 0; off >>= 1) s += __shfl_xor(s, off, 64);
  if (lane == 0) red[wid] = s;
  __syncthreads();
  float mean = (red[0] + red[1] + red[2] + red[3]) * 0.00390625f;
  float dv = v - mean;
  float s2 = dv * dv;
#pragma unroll
  for (int off = 32; off > 0; off >>= 1) s2 += __shfl_xor(s2, off, 64);
  if (lane == 0) red[4 + wid] = s2;
  __syncthreads();
  float var = (red[4] + red[5] + red[6] + red[7]) * 0.00390625f;
  float y = dv * (1.0f / sqrtf(var + 1e-5f)) * sc[d] + bi[d];
  Y[idx] = y;
  if (oh) {
    unsigned short hh, ll;
    bf16_split(y, hh, ll);
    oh[idx] = hh; ol[idx] = ll;
  }
}

// ---------------- LayerNorm + plane split + fused router<E> ----------------
template <int E>
__global__ __launch_bounds__(256) void k_ln_router(
    const float* __restrict__ Xin, const float* __restrict__ R,
    const float* __restrict__ sc, const float* __restrict__ bi, float* __restrict__ Y,
    unsigned short* __restrict__ oh, unsigned short* __restrict__ ol,
    const float* __restrict__ gw, const float* __restrict__ gb,
    float* __restrict__ probs, int* __restrict__ ti, float* __restrict__ tw)
{
  int t = blockIdx.x, d = threadIdx.x;
  size_t idx = (size_t)t * 256 + d;
  float v = Xin[idx] + R[idx];
  __shared__ float red[8];
  __shared__ float redg[4 * E];
  int lane = d & 63, wid = d >> 6;
  float s = v;
#pragma unroll
  for (int off = 32; off > 0; off >>= 1) s += __shfl_xor(s, off, 64);
  if (lane == 0) red[wid] = s;
  __syncthreads();
  float mean = (red[0] + red[1] + red[2] + red[3]) * 0.00390625f;
  float dv = v - mean;
  float s2 = dv * dv;
#pragma unroll
  for (int off = 32; off > 0; off >>= 1) s2 += __shfl_xor(s2, off, 64);
  if (lane == 0) red[4 + wid] = s2;
  __syncthreads();
  float var = (red[4] + red[5] + red[6] + red[7]) * 0.00390625f;
  float y = dv * (1.0f / sqrtf(var + 1e-5f)) * sc[d] + bi[d];
  Y[idx] = y;
  unsigned short hh, ll;
  bf16_split(y, hh, ll);
  oh[idx] = hh; ol[idx] = ll;
#pragma unroll
  for (int e = 0; e < E; ++e) {
    float g = y * gw[e * 256 + d];
#pragma unroll
    for (int off = 32; off > 0; off >>= 1) g += __shfl_xor(g, off, 64);
    if (lane == 0) redg[wid * E + e] = g;
  }
  __syncthreads();
  if (d == 0) {
    float p[E];
    float m = -1e30f;
#pragma unroll
    for (int e = 0; e < E; ++e) {
      p[e] = redg[e] + redg[E + e] + redg[2 * E + e] + redg[3 * E + e] + gb[e];
      m = fmaxf(m, p[e]);
    }
    float sum = 0.f;
#pragma unroll
    for (int e = 0; e < E; ++e) { p[e] = expf(p[e] - m); sum += p[e]; }
    float inv = 1.f / sum;
#pragma unroll
    for (int e = 0; e < E; ++e) { p[e] *= inv; probs[(size_t)t * E + e] = p[e]; }
    float v1 = p[0]; int i1 = 0;
#pragma unroll
    for (int e = 1; e < E; ++e) if (p[e] > v1) { v1 = p[e]; i1 = e; }
    float v2 = -1.f; int i2 = 0;
#pragma unroll
    for (int e = 0; e < E; ++e) if (e != i1 && p[e] > v2) { v2 = p[e]; i2 = e; }
    float sx = v1 + v2;
    ti[t * 2] = i1; ti[t * 2 + 1] = i2;
    tw[t * 2] = v1 / sx; tw[t * 2 + 1] = v2 / sx;
  }
}

// ---------------- fused MoE-combine + LayerNorm (+ optional plane split) ----------------
__global__ __launch_bounds__(256) void k_ln_comb(
    const float* __restrict__ Xin, const float* __restrict__ Yb, int ldY,
    const int* __restrict__ slotmap, const float* __restrict__ tw,
    const float* __restrict__ sc, const float* __restrict__ bi, float* __restrict__ Y,
    unsigned short* __restrict__ oh, unsigned short* __restrict__ ol)
{
  int t = blockIdx.x, d = threadIdx.x;
  size_t idx = (size_t)t * 256 + d;
  int s0 = slotmap[2 * t], s1 = slotmap[2 * t + 1];
  float w0 = tw[2 * t], w1 = tw[2 * t + 1];
  float v = w0 * Yb[(size_t)s0 * ldY + d] + w1 * Yb[(size_t)s1 * ldY + d];
  if (Xin) v += Xin[idx];
  __shared__ float red[8];
  int lane = d & 63, wid = d >> 6;
  float s = v;
#pragma unroll
  for (int off = 32; off > 0; off >>= 1) s += __shfl_xor(s, off, 64);
  if (lane == 0) red[wid] = s;
  __syncthreads();
  float mean = (red[0] + red[1] + red[2] + red[3]) * 0.00390625f;
  float dv = v - mean;
  float s2 = dv * dv;
#pragma unroll
  for (int off = 32; off > 0; off >>= 1) s2 += __shfl_xor(s2, off, 64);
  if (lane == 0) red[4 + wid] = s2;
  __syncthreads();
  float var = (red[4] + red[5] + red[6] + red[7]) * 0.00390625f;
  float y = dv * (1.0f / sqrtf(var + 1e-5f)) * sc[d] + bi[d];
  Y[idx] = y;
  if (oh) {
    unsigned short hh, ll;
    bf16_split(y, hh, ll);
    oh[idx] = hh; ol[idx] = ll;
  }
}

// ---------------- count + 128-aligned scan + padding init ----------------
template <int E>
__global__ __launch_bounds__(256) void k_count_scan(
    const int* __restrict__ ti, int T,
    int* __restrict__ offs, int* __restrict__ cnt2, int* __restrict__ tok)
{
  __shared__ int sc[8];
  __shared__ int soffs[9];
  __shared__ int scnt[8];
  int tid = threadIdx.x;
  if (tid < 8) { sc[tid] = 0; cnt2[tid] = 0; }
  __syncthreads();
  int c[E];
#pragma unroll
  for (int k = 0; k < E; ++k) c[k] = 0;
  const int4* t4 = (const int4*)ti;
  for (int i = tid; i < (2 * T) >> 2; i += 256) {
    int4 v = t4[i];
#pragma unroll
    for (int k = 0; k < E; ++k) {
      c[k] += (v.x == k) ? 1 : 0;
      c[k] += (v.y == k) ? 1 : 0;
      c[k] += (v.z == k) ? 1 : 0;
      c[k] += (v.w == k) ? 1 : 0;
    }
  }
#pragma unroll
  for (int k = 0; k < E; ++k) {
    int v = c[k];
#pragma unroll
    for (int off = 32; off > 0; off >>= 1) v += __shfl_xor(v, off, 64);
    if ((tid & 63) == 0) atomicAdd(&sc[k], v);
  }
  __syncthreads();
  if (tid == 0) {
    int o = 0;
    for (int e = 0; e < E; ++e) {
      soffs[e] = o; scnt[e] = sc[e];
      o += (sc[e] + 127) & ~127;          // 128-aligned for MFMA tiles
    }
    soffs[E] = o;
  }
  __syncthreads();
  if (tid <= E) offs[tid] = soffs[tid];
  for (int e = 0; e < E; ++e) {
    int s0 = soffs[e] + scnt[e], s1 = soffs[e + 1];
    for (int i = s0 + tid; i < s1; i += 256) tok[i] = -1;
  }
}

// ---------------- fill expert slot lists + token->slot map ----------------
__global__ __launch_bounds__(256) void k_fill(
    const int* __restrict__ ti, int T,
    const int* __restrict__ offs, int* __restrict__ cnt2,
    int* __restrict__ tok, int* __restrict__ slotmap)
{
  __shared__ int lcnt[8];
  __shared__ int lbase[8];
  int tid = threadIdx.x;
  if (tid < 8) lcnt[tid] = 0;
  __syncthreads();
  int t = blockIdx.x * 256 + tid;
  int e0 = 0, e1 = 0, p0 = 0, p1 = 0;
  bool act = (t < T);
  if (act) {
    e0 = ti[t * 2]; e1 = ti[t * 2 + 1];
    p0 = atomicAdd(&lcnt[e0], 1);
    p1 = atomicAdd(&lcnt[e1], 1);
  }
  __syncthreads();
  if (tid < 8) lbase[tid] = atomicAdd(&cnt2[tid], lcnt[tid]);
  __syncthreads();
  if (act) {
    int s0 = offs[e0] + lbase[e0] + p0;
    tok[s0] = t; slotmap[t * 2] = s0;
    int s1 = offs[e1] + lbase[e1] + p1;
    tok[s1] = t; slotmap[t * 2 + 1] = s1;
  }
}

// ---------------- final logits ----------------
__global__ __launch_bounds__(256) void k_final(
    const float* __restrict__ FH, const float* __restrict__ w2,
    const float* __restrict__ b2, float* __restrict__ out, int T)
{
  int lane = threadIdx.x & 63, wid = threadIdx.x >> 6;
  int t = blockIdx.x * 4 + wid;
  if (t >= T) return;
  float4 h = *(const float4*)(FH + (size_t)t * 256 + lane * 4);
  float4 w = *(const float4*)(w2 + lane * 4);
  float s = h.x * w.x + h.y * w.y + h.z * w.z + h.w * w.w;
#pragma unroll
  for (int off = 32; off > 0; off >>= 1) s += __shfl_xor(s, off, 64);
  if (lane == 0) out[t] = s + b2[0];
}

// ---------------- aux load-balance loss ----------------
__global__ __launch_bounds__(256) void k_aux(
    const float* __restrict__ p0, const float* __restrict__ p1,
    const float* __restrict__ pi, float* __restrict__ out_aux)
{
  __shared__ float red[256];
  int tid = threadIdx.x;
  float aux = 0.f;
  for (int r = 0; r < 2; ++r) {
    const float* P = (r == 0) ? p0 : p1;
    float loc[4] = {0.f, 0.f, 0.f, 0.f};
    for (int t = tid; t < T_U; t += 256) {
#pragma unroll
      for (int e = 0; e < 4; ++e) loc[e] += P[t * 4 + e];
    }
    float contrib = 0.f;
    for (int e = 0; e < 4; ++e) {
      red[tid] = loc[e];
      __syncthreads();
      for (int s = 128; s > 0; s >>= 1) { if (tid < s) red[tid] += red[tid + s]; __syncthreads(); }
      if (tid == 0) { float d = red[0] * (1.f / T_U) - 0.125f; contrib += d * d; }
      __syncthreads();
    }
    if (tid == 0) aux += contrib * 0.25f;
  }
  {
    float loc[8] = {};
    for (int t = tid; t < T_I; t += 256) {
#pragma unroll
      for (int e = 0; e < 8; ++e) loc[e] += pi[t * 8 + e];
    }
    float contrib = 0.f;
    for (int e = 0; e < 8; ++e) {
      red[tid] = loc[e];
      __syncthreads();
      for (int s = 128; s > 0; s >>= 1) { if (tid < s) red[tid] += red[tid + s]; __syncthreads(); }
      if (tid == 0) { float d = red[0] * (1.f / T_I) - 0.125f; contrib += d * d; }
      __syncthreads();
    }
    if (tid == 0) aux += contrib * 0.125f;
  }
  if (tid == 0) *out_aux = aux;
}

// =======================================================================
extern "C" void kernel_launch(void* const* d_in, const int* in_sizes, int n_in,
                              void* d_out, int out_size, void* d_ws, size_t ws_size,
                              hipStream_t stream)
{
  (void)in_sizes; (void)n_in; (void)out_size;
  const int*   history  = (const int*)d_in[0];
  const int*   cand     = (const int*)d_in[1];
  const int*   catid    = (const int*)d_in[2];
  const float* item_emb = (const float*)d_in[3];
  const float* cat_emb  = (const float*)d_in[4];
  const float* ub_in_w  = (const float*)d_in[5];
  const float* ub_in_b  = (const float*)d_in[6];
  const float* ub_out_w = (const float*)d_in[7];
  const float* ub_out_b = (const float*)d_in[8];
  const float* ub_n1_s  = (const float*)d_in[9];
  const float* ub_n1_b  = (const float*)d_in[10];
  const float* ub_n2_s  = (const float*)d_in[11];
  const float* ub_n2_b  = (const float*)d_in[12];
  const float* ub_gate_w= (const float*)d_in[13];
  const float* ub_gate_b= (const float*)d_in[14];
  const float* ub_e_w1  = (const float*)d_in[15];
  const float* ub_e_b1  = (const float*)d_in[16];
  const float* ub_e_w2  = (const float*)d_in[17];
  const float* ub_e_b2  = (const float*)d_in[18];
  const float* un_s     = (const float*)d_in[19];
  const float* un_b     = (const float*)d_in[20];
  const float* im_gate_w= (const float*)d_in[21];
  const float* im_gate_b= (const float*)d_in[22];
  const float* im_e_w1  = (const float*)d_in[23];
  const float* im_e_b1  = (const float*)d_in[24];
  const float* im_e_w2  = (const float*)d_in[25];
  const float* im_e_b2  = (const float*)d_in[26];
  const float* in_s     = (const float*)d_in[27];
  const float* in_b     = (const float*)d_in[28];
  const float* ca_in_w  = (const float*)d_in[29];
  const float* ca_in_b  = (const float*)d_in[30];
  const float* ca_out_w = (const float*)d_in[31];
  const float* ca_out_b = (const float*)d_in[32];
  const float* fm_w1    = (const float*)d_in[33];
  const float* fm_b1    = (const float*)d_in[34];
  const float* fm_w2    = (const float*)d_in[35];
  const float* fm_b2    = (const float*)d_in[36];
  float* out = (float*)d_out;

  float* W = (float*)d_ws;
  size_t o = 0;
  auto alloc = [&](size_t n) { size_t r = o; o += (n + 63) & ~(size_t)63; return r; };
  const size_t oX    = alloc((size_t)T_U * 256);
  const size_t oQKV  = alloc((size_t)T_U * 768);   // region A (reuse: H planes / Kbuf,Vbuf)
  const size_t oAO   = alloc((size_t)T_U * 256);   // region B (H spillover)
  const size_t oEXT  = alloc(300000);              // region C (H tail)
  const size_t oTMP  = alloc((size_t)T_U * 256);
  const size_t oP0   = alloc((size_t)T_U * 4);
  const size_t oP1   = alloc((size_t)T_U * 4);
  const size_t oPI   = alloc((size_t)T_I * 8);
  const size_t oTW   = alloc((size_t)T_U * 2);
  const size_t oSM   = alloc((size_t)T_U * 2);     // int slotmap
  const size_t oTI   = alloc((size_t)T_U * 2);     // int
  const size_t oTOK  = alloc(CAP_U);               // int
  const size_t oCNT  = alloc(64);                  // int cnt2[8]|offs[9]
  const size_t oZERO = alloc(512);                 // 2KB zero region for gll pads
  const size_t oIE   = alloc((size_t)T_I * 256);
  const size_t oITEM = alloc((size_t)T_I * 256);
  const size_t oQB   = alloc((size_t)T_I * 256);
  const size_t oOB   = alloc((size_t)T_I * 256);
  const size_t oTAW  = alloc((size_t)T_I * 256);
  const size_t oFH   = alloc((size_t)T_I * 256);
  const size_t oWB   = alloc(4915200);             // bf16 weight arena: 2 planes x 4,915,200 shorts
  const size_t oCVT  = alloc((size_t)T_U * 256);   // activation hi/lo planes (user)
  const size_t oCVI  = alloc((size_t)T_I * 256);   // activation hi/lo planes (item)
  (void)oEXT;
  if (ws_size < o * sizeof(float)) {
    k_sentinel<<<1, 1, 0, stream>>>(out);
    return;
  }

  float* X    = W + oX;
  float* QKV  = W + oQKV;
  float* AO   = W + oAO;
  float* TMP  = W + oTMP;
  float* P0   = W + oP0;
  float* P1   = W + oP1;
  float* PI   = W + oPI;
  float* TWb  = W + oTW;
  int*   SLOT = (int*)(W + oSM);
  int*   TIb  = (int*)(W + oTI);
  int*   TOKb = (int*)(W + oTOK);
  int*   CNT  = (int*)(W + oCNT);
  int*   CNT2 = CNT;
  int*   OFFS = CNT + 8;
  const unsigned short* ZB = (const unsigned short*)(W + oZERO);
  float* IE   = W + oIE;
  float* ITEM = W + oITEM;
  float* QB   = W + oQB;
  float* OB   = W + oOB;
  float* TAW  = W + oTAW;
  float* FH   = W + oFH;
  float* Kbuf = QKV;
  float* Vbuf = QKV + (size_t)T_U * 256;
  (void)AO;

  // bf16 weight arena (per-plane short offsets)
  unsigned short* WH = (unsigned short*)(W + oWB);
  unsigned short* WL = WH + 4915200;
  const size_t off_in = 0, off_out = 393216, off_ew1 = 524288, off_ew2 = 1572864,
               off_iw1 = 2621440, off_iw2 = 3670016, off_ca = 4718592;
  // activation planes
  unsigned short* CVH = (unsigned short*)(W + oCVT);
  unsigned short* CVL = CVH + (size_t)T_U * 256;
  unsigned short* CIH = (unsigned short*)(W + oCVI);
  unsigned short* CIL = CIH + (size_t)T_I * 256;
  // H planes (user MoE) alias region A+B+C; Y fp32 aliases the Hlo plane.
  unsigned short* Hhi = (unsigned short*)(W + oQKV);
  unsigned short* Hlo = Hhi + (size_t)CAP_U * 512;
  float* Yu = (float*)Hlo;                          // CAP_U x 256 fp32
  unsigned short* iHhi = (unsigned short*)(W + oQKV);
  unsigned short* iHlo = iHhi + (size_t)CAP_I * 512;
  float* Yi = (float*)iHlo;                         // CAP_I x 256 fp32

  // 0) fused weight conversions + zero pad-source (1 launch)
  k_cvt_all<<<4800, 256, 0, stream>>>(ub_in_w, ub_out_w, ub_e_w1, ub_e_w2,
                                      im_e_w1, im_e_w2, ca_in_w, WH, WL, W + oZERO);

  // 1) embedding + rope (+ X planes)
  k_embed_rope<<<T_U, 256, 0, stream>>>(history, item_emb, X, CVH, CVL);

  // 2) user transformer layers
  for (int l = 0; l < 2; ++l) {
    k_mfmm<<<dim3(6, 100), 256, 0, stream>>>(CVH, CVL, nullptr, nullptr, 0,
        WH + off_in + (size_t)l * 196608, WL + off_in + (size_t)l * 196608,
        ub_in_b + l * 768, ZB, QKV, nullptr, nullptr, 768, 256, 768, 0);
    k_attn_mfma<<<512, 256, 0, stream>>>(QKV, CVH, CVL);
    k_mfmm<<<dim3(2, 100), 256, 0, stream>>>(CVH, CVL, nullptr, nullptr, 0,
        WH + off_out + (size_t)l * 65536, WL + off_out + (size_t)l * 65536,
        ub_out_b + l * 256, ZB, TMP, nullptr, nullptr, 256, 256, 256, 0);
    // n1 LN + planes + fused router<4>
    k_ln_router<4><<<T_U, 256, 0, stream>>>(X, TMP, ub_n1_s + l * 256, ub_n1_b + l * 256,
        X, CVH, CVL, ub_gate_w + (size_t)l * 4 * 256, ub_gate_b + l * 4,
        (l == 0) ? P0 : P1, TIb, TWb);
    k_count_scan<4><<<1, 256, 0, stream>>>(TIb, T_U, OFFS, CNT2, TOKb);
    k_fill<<<T_U / 256, 256, 0, stream>>>(TIb, T_U, OFFS, CNT2, TOKb, SLOT);
    k_mfmm<<<dim3(4, CAP_U / 128), 256, 0, stream>>>(CVH, CVL, TOKb, OFFS, 4,
        WH + off_ew1 + (size_t)l * 524288, WL + off_ew1 + (size_t)l * 524288,
        ub_e_b1 + (size_t)l * 2048, ZB, nullptr, Hhi, Hlo, 512, 256, 512, 1);
    k_mfmm_y<<<dim3(1, CAP_U / 64), 256, 0, stream>>>(Hhi, Hlo, OFFS, 4,
        WH + off_ew2 + (size_t)l * 524288, WL + off_ew2 + (size_t)l * 524288,
        ub_e_b2 + (size_t)l * 1024, Yu, 512);
    k_ln_comb<<<T_U, 256, 0, stream>>>(X, Yu, 256, SLOT, TWb,
        ub_n2_s + l * 256, ub_n2_b + l * 256, X,
        (l == 0) ? CVH : nullptr, (l == 0) ? CVL : nullptr);
  }

  // 3) history final LN (+ planes for xattn K/V projections)
  k_ln<<<T_U, 256, 0, stream>>>(X, nullptr, un_s, un_b, X, CVH, CVL);

  // 4) item tower (embed + planes + fused router<8>)
  k_item_embed_router<<<T_I, 256, 0, stream>>>(cand, catid, item_emb, cat_emb,
      IE, CIH, CIL, im_gate_w, im_gate_b, PI, TIb, TWb);
  k_count_scan<8><<<1, 256, 0, stream>>>(TIb, T_I, OFFS, CNT2, TOKb);
  k_fill<<<T_I / 256, 256, 0, stream>>>(TIb, T_I, OFFS, CNT2, TOKb, SLOT);
  k_mfmm<<<dim3(4, CAP_I / 128), 256, 0, stream>>>(CIH, CIL, TOKb, OFFS, 8,
      WH + off_iw1, WL + off_iw1, im_e_b1, ZB, nullptr, iHhi, iHlo, 512, 256, 512, 1);
  k_mfmm_y<<<dim3(1, CAP_I / 64), 256, 0, stream>>>(iHhi, iHlo, OFFS, 8,
      WH + off_iw2, WL + off_iw2, im_e_b2, Yi, 512);
  k_ln_comb<<<T_I, 256, 0, stream>>>(nullptr, Yi, 256, SLOT, TWb, in_s, in_b, ITEM,
                                     nullptr, nullptr);

  // 5) cross attention
  k_gemm<<<dim3(4, 16), 256, 0, stream>>>(ITEM, nullptr, ca_in_w, ca_in_b, QB,
                                          T_I, 256, 256, 0);
  k_mfmm<<<dim3(2, 100), 256, 0, stream>>>(CVH, CVL, nullptr, nullptr, 0,
      WH + off_ca + 65536, WL + off_ca + 65536, ca_in_b + 256,
      ZB, Kbuf, nullptr, nullptr, 256, 256, 256, 0);
  k_mfmm<<<dim3(2, 100), 256, 0, stream>>>(CVH, CVL, nullptr, nullptr, 0,
      WH + off_ca + 131072, WL + off_ca + 131072, ca_in_b + 512,
      ZB, Vbuf, nullptr, nullptr, 256, 256, 256, 0);
  k_xattn<<<512, 256, 0, stream>>>(QB, Kbuf, Vbuf, OB);
  k_gemm<<<dim3(4, 16), 256, 0, stream>>>(OB, nullptr, ca_out_w, ca_out_b, TAW,
                                          T_I, 256, 256, 0);

  // 6) fusion MLP (concat fused via dual-A) + logits
  k_gemm<<<dim3(4, 16), 256, 0, stream>>>(TAW, ITEM, fm_w1, fm_b1, FH,
                                          T_I, 256, 512, 1);
  k_final<<<T_I / 4, 256, 0, stream>>>(FH, fm_w2, fm_b2, out, T_I);

  // 7) aux loss
  k_aux<<<1, 256, 0, stream>>>(P0, P1, PI, out + 1024);
}